// Round 1
// baseline (1260.289 us; speedup 1.0000x reference)
//
#include <hip/hip_runtime.h>
#include <math.h>

typedef unsigned short u16;
typedef unsigned int u32;
typedef __bf16 bf16x8 __attribute__((ext_vector_type(8)));
typedef __bf16 bf16x4 __attribute__((ext_vector_type(4)));
typedef float f32x4 __attribute__((ext_vector_type(4)));

#define DIM 2048
#define NHEADS 16
#define NKVH 8
#define HD 128
#define RANK 16
#define INNER 5632
#define BB 2
#define SS 2048
#define NROWS (BB*SS)
#define EPS 1e-5f
#define QSCALE 0.08838834764831845f  /* 1/sqrt(128) */

__device__ inline float bf2f(u16 u){ u32 x = ((u32)u)<<16; float f; __builtin_memcpy(&f,&x,4); return f; }
__device__ inline u16 f2bf(float f){ u32 u; __builtin_memcpy(&u,&f,4); u32 r = u + 0x7fffu + ((u>>16)&1u); return (u16)(r>>16); }
__device__ inline u32 pack2(float a, float b){ return (u32)f2bf(a) | ((u32)f2bf(b)<<16); }

__device__ inline float blockReduceSum(float v){
  __shared__ float r[4];
  #pragma unroll
  for(int o=1;o<64;o<<=1) v += __shfl_xor(v, o);
  int wv = threadIdx.x>>6;
  __syncthreads();
  if((threadIdx.x&63)==0) r[wv] = v;
  __syncthreads();
  return r[0]+r[1]+r[2]+r[3];
}

__device__ inline float2 blockReduceSum2(float a, float b){
  __shared__ float ra[4], rb[4];
  #pragma unroll
  for(int o=1;o<64;o<<=1){ a += __shfl_xor(a, o); b += __shfl_xor(b, o); }
  int wv = threadIdx.x>>6;
  __syncthreads();
  if((threadIdx.x&63)==0){ ra[wv]=a; rb[wv]=b; }
  __syncthreads();
  return make_float2(ra[0]+ra[1]+ra[2]+ra[3], rb[0]+rb[1]+rb[2]+rb[3]);
}

// ---------------- RMSNorm: f32 in -> bf16 out (row = block) ----------------
__global__ __launch_bounds__(256) void k_rms(const float* __restrict__ x,
                                             const float* __restrict__ w,
                                             u16* __restrict__ out){
  size_t base = (size_t)blockIdx.x*DIM;
  int tid = threadIdx.x;
  float4 v0 = ((const float4*)(x+base))[tid*2];
  float4 v1 = ((const float4*)(x+base))[tid*2+1];
  float ss = v0.x*v0.x+v0.y*v0.y+v0.z*v0.z+v0.w*v0.w
           + v1.x*v1.x+v1.y*v1.y+v1.z*v1.z+v1.w*v1.w;
  ss = blockReduceSum(ss);
  float rstd = rsqrtf(ss*(1.0f/DIM) + EPS);
  float4 w0 = ((const float4*)w)[tid*2];
  float4 w1 = ((const float4*)w)[tid*2+1];
  uint4 st;
  st.x = pack2(v0.x*w0.x*rstd, v0.y*w0.y*rstd);
  st.y = pack2(v0.z*w0.z*rstd, v0.w*w0.w*rstd);
  st.z = pack2(v1.x*w1.x*rstd, v1.y*w1.y*rstd);
  st.w = pack2(v1.z*w1.z*rstd, v1.w*w1.w*rstd);
  *(uint4*)&out[base + tid*8] = st;
}

// ---------------- LoRA-A: out[M][NM*16] = Xbf16[M][DIM] @ [A0|A1|A2] ----------------
// 16 rows/block, 16-way k-split per row, shfl reduce.
template<int NM>
__global__ __launch_bounds__(256) void k_loraA(const u16* __restrict__ X,
                                               const float* __restrict__ A0,
                                               const float* __restrict__ A1,
                                               const float* __restrict__ A2,
                                               float* __restrict__ out){
  constexpr int N = NM*16;
  int tid = threadIdx.x;
  int row = blockIdx.x*16 + (tid>>4);
  int ks  = tid&15;
  float acc[N];
  #pragma unroll
  for(int c=0;c<N;c++) acc[c]=0.f;
  const u16* xp = X + (size_t)row*DIM + ks*128;
  for(int i=0;i<128;i++){
    int k = ks*128 + i;
    float xv = bf2f(xp[i]);
    {
      const float4* a = (const float4*)(A0 + (size_t)k*16);
      #pragma unroll
      for(int q=0;q<4;q++){ float4 t=a[q];
        acc[q*4+0]=fmaf(xv,t.x,acc[q*4+0]); acc[q*4+1]=fmaf(xv,t.y,acc[q*4+1]);
        acc[q*4+2]=fmaf(xv,t.z,acc[q*4+2]); acc[q*4+3]=fmaf(xv,t.w,acc[q*4+3]); }
    }
    if constexpr (NM>1){
      const float4* a = (const float4*)(A1 + (size_t)k*16);
      #pragma unroll
      for(int q=0;q<4;q++){ float4 t=a[q];
        acc[16+q*4+0]=fmaf(xv,t.x,acc[16+q*4+0]); acc[16+q*4+1]=fmaf(xv,t.y,acc[16+q*4+1]);
        acc[16+q*4+2]=fmaf(xv,t.z,acc[16+q*4+2]); acc[16+q*4+3]=fmaf(xv,t.w,acc[16+q*4+3]); }
    }
    if constexpr (NM>2){
      const float4* a = (const float4*)(A2 + (size_t)k*16);
      #pragma unroll
      for(int q=0;q<4;q++){ float4 t=a[q];
        acc[32+q*4+0]=fmaf(xv,t.x,acc[32+q*4+0]); acc[32+q*4+1]=fmaf(xv,t.y,acc[32+q*4+1]);
        acc[32+q*4+2]=fmaf(xv,t.z,acc[32+q*4+2]); acc[32+q*4+3]=fmaf(xv,t.w,acc[32+q*4+3]); }
    }
  }
  #pragma unroll
  for(int o=1;o<16;o<<=1){
    #pragma unroll
    for(int c=0;c<N;c++) acc[c] += __shfl_xor(acc[c], o);
  }
  if(ks==0){
    #pragma unroll
    for(int c=0;c<N;c++) out[(size_t)row*N + c] = acc[c];
  }
}

// ---------------- Q path: LoRA-B + LayerNorm + RoPE + scale -> bf16 ----------------
__global__ __launch_bounds__(256) void k_qb(const float* __restrict__ xa,
                                            const float* __restrict__ wqb,
                                            const float* __restrict__ bq,
                                            const float* __restrict__ nqw,
                                            const float* __restrict__ nqb,
                                            const float* __restrict__ cosT,
                                            const float* __restrict__ sinT,
                                            u16* __restrict__ qout){
  __shared__ u16 wl[16*2048];  // 64 KB, bf16 weights
  int tid = threadIdx.x;
  for(int ii=0;ii<32;ii++){
    int f4 = tid + 256*ii;
    float4 v = ((const float4*)wqb)[f4];
    uint2 st; st.x = pack2(v.x,v.y); st.y = pack2(v.z,v.w);
    *(uint2*)&wl[f4*4] = st;
  }
  __syncthreads();
  int j0 = tid*8;
  float bqv[8], nwv[8], nbv[8];
  #pragma unroll
  for(int e=0;e<8;e++){ bqv[e]=bq[j0+e]; nwv[e]=nqw[j0+e]; nbv[e]=nqb[j0+e]; }
  int i0 = (j0&127)>>1;
  for(int rr=0;rr<16;rr++){
    int row = blockIdx.x*16 + rr;
    float xq[16];
    #pragma unroll
    for(int r=0;r<16;r++) xq[r] = xa[(size_t)row*48 + r];
    float pre[8];
    #pragma unroll
    for(int e=0;e<8;e++) pre[e]=0.f;
    #pragma unroll
    for(int r=0;r<16;r++){
      bf16x8 wv = *(const bf16x8*)&wl[r*2048 + j0];
      #pragma unroll
      for(int e=0;e<8;e++) pre[e] = fmaf(xq[r], (float)wv[e], pre[e]);
    }
    #pragma unroll
    for(int e=0;e<8;e++) pre[e] = pre[e]*0.0625f + bqv[e];
    float s=0.f, sq=0.f;
    #pragma unroll
    for(int e=0;e<8;e++){ s+=pre[e]; sq+=pre[e]*pre[e]; }
    float2 red = blockReduceSum2(s, sq);
    float mu = red.x*(1.0f/DIM);
    float var = red.y*(1.0f/DIM) - mu*mu;
    float rstd = rsqrtf(var + EPS);
    float qn[8];
    #pragma unroll
    for(int e=0;e<8;e++) qn[e] = (pre[e]-mu)*rstd*nwv[e] + nbv[e];
    int spos = row & (SS-1);
    const float* cp = cosT + spos*64;
    const float* sp = sinT + spos*64;
    uint4 st;
    u32 pk[4];
    #pragma unroll
    for(int p=0;p<4;p++){
      float c = cp[i0+p], sn = sp[i0+p];
      float x0 = qn[2*p], x1 = qn[2*p+1];
      pk[p] = pack2((x0*c - x1*sn)*QSCALE, (x0*sn + x1*c)*QSCALE);
    }
    st.x=pk[0]; st.y=pk[1]; st.z=pk[2]; st.w=pk[3];
    *(uint4*)&qout[(size_t)row*2048 + j0] = st;
  }
}

// ---------------- K/V path: LoRA-B (+LN+RoPE for K) -> bf16 ----------------
__global__ __launch_bounds__(256) void k_kvb(const float* __restrict__ xa,
                                             const float* __restrict__ wkb,
                                             const float* __restrict__ bk,
                                             const float* __restrict__ nkw,
                                             const float* __restrict__ nkb,
                                             const float* __restrict__ wvb,
                                             const float* __restrict__ bv,
                                             const float* __restrict__ cosT,
                                             const float* __restrict__ sinT,
                                             u16* __restrict__ kout,
                                             u16* __restrict__ vout){
  __shared__ u16 wl[2*16*1024];  // 64 KB: [0,16K)=wk_b, [16K,32K)=wv_b
  int tid = threadIdx.x;
  for(int ii=0;ii<32;ii++){
    int f4 = tid + 256*ii;
    float4 v = (f4 < 4096) ? ((const float4*)wkb)[f4] : ((const float4*)wvb)[f4-4096];
    uint2 st; st.x = pack2(v.x,v.y); st.y = pack2(v.z,v.w);
    *(uint2*)&wl[f4*4] = st;
  }
  __syncthreads();
  int j0 = tid*4;
  float bkv[4], nwv[4], nbv[4], bvv[4];
  #pragma unroll
  for(int e=0;e<4;e++){ bkv[e]=bk[j0+e]; nwv[e]=nkw[j0+e]; nbv[e]=nkb[j0+e]; bvv[e]=bv[j0+e]; }
  int i0 = (j0&127)>>1;
  for(int rr=0;rr<16;rr++){
    int row = blockIdx.x*16 + rr;
    float xk[16], xv[16];
    #pragma unroll
    for(int r=0;r<16;r++){ xk[r]=xa[(size_t)row*48+16+r]; xv[r]=xa[(size_t)row*48+32+r]; }
    float pk_[4], pv_[4];
    #pragma unroll
    for(int e=0;e<4;e++){ pk_[e]=0.f; pv_[e]=0.f; }
    #pragma unroll
    for(int r=0;r<16;r++){
      bf16x4 wk4 = *(const bf16x4*)&wl[r*1024 + j0];
      bf16x4 wv4 = *(const bf16x4*)&wl[16384 + r*1024 + j0];
      #pragma unroll
      for(int e=0;e<4;e++){ pk_[e]=fmaf(xk[r],(float)wk4[e],pk_[e]); pv_[e]=fmaf(xv[r],(float)wv4[e],pv_[e]); }
    }
    #pragma unroll
    for(int e=0;e<4;e++){ pk_[e]=pk_[e]*0.0625f + bkv[e]; pv_[e]=pv_[e]*0.0625f + bvv[e]; }
    float s=0.f, sq=0.f;
    #pragma unroll
    for(int e=0;e<4;e++){ s+=pk_[e]; sq+=pk_[e]*pk_[e]; }
    float2 red = blockReduceSum2(s, sq);
    float mu = red.x*(1.0f/1024.0f);
    float var = red.y*(1.0f/1024.0f) - mu*mu;
    float rstd = rsqrtf(var + EPS);
    float kn[4];
    #pragma unroll
    for(int e=0;e<4;e++) kn[e] = (pk_[e]-mu)*rstd*nwv[e] + nbv[e];
    int spos = row & (SS-1);
    const float* cp = cosT + spos*64;
    const float* sp = sinT + spos*64;
    uint2 stk;
    { float c=cp[i0],   sn=sp[i0];   stk.x = pack2(kn[0]*c - kn[1]*sn, kn[0]*sn + kn[1]*c); }
    { float c=cp[i0+1], sn=sp[i0+1]; stk.y = pack2(kn[2]*c - kn[3]*sn, kn[2]*sn + kn[3]*c); }
    *(uint2*)&kout[(size_t)row*1024 + j0] = stk;
    uint2 stv; stv.x = pack2(pv_[0],pv_[1]); stv.y = pack2(pv_[2],pv_[3]);
    *(uint2*)&vout[(size_t)row*1024 + j0] = stv;
  }
}

// ---------------- Flash attention + residual add -> d_out (f32 h) ----------------
// grid 512 = b(2) x h(16) x qtile(16); block 256 = 4 waves x 32 q-rows each.
__global__ __launch_bounds__(256,2) void k_attn(const u16* __restrict__ qb,
                                                const u16* __restrict__ kb,
                                                const u16* __restrict__ vb,
                                                const float* __restrict__ resid,
                                                float* __restrict__ out){
  __shared__ u16 Klds[64*136];     // [key][d], pad 136 -> 2-way-max conflicts
  __shared__ u16 Vt[128*72];       // [d][key], pad 72
  __shared__ u16 Plds[4][32*72];   // per-wave P, [qrow][key], pad 72
  int bid = blockIdx.x;
  int qt = bid & 15;
  int h  = (bid>>4) & 15;
  int b  = bid>>8;
  int kvh = h>>1;
  int tid = threadIdx.x;
  int w = tid>>6, lane = tid&63;
  int lg = lane>>4, l16 = lane&15;

  bf16x8 qf[2][4];
  #pragma unroll
  for(int m=0;m<2;m++){
    int s = qt*128 + w*32 + m*16 + l16;
    const u16* qp = qb + ((size_t)(b*SS + s))*DIM + h*HD + lg*8;
    qf[m][0] = *(const bf16x8*)(qp);
    qf[m][1] = *(const bf16x8*)(qp+32);
    qf[m][2] = *(const bf16x8*)(qp+64);
    qf[m][3] = *(const bf16x8*)(qp+96);
  }
  f32x4 acc[2][8];
  #pragma unroll
  for(int m=0;m<2;m++)
    #pragma unroll
    for(int n=0;n<8;n++) acc[m][n] = (f32x4){0.f,0.f,0.f,0.f};
  float mrow[2][4], lrow[2][4];
  #pragma unroll
  for(int m=0;m<2;m++)
    #pragma unroll
    for(int r=0;r<4;r++){ mrow[m][r] = -INFINITY; lrow[m][r] = 0.f; }

  for(int kt=0; kt<SS/64; kt++){
    // stage K [key][d] and V^T [d][key]
    #pragma unroll
    for(int jj=0;jj<4;jj++){
      int mi = tid + 256*jj;
      int key = mi>>4, d0 = (mi&15)*8;
      size_t gidx = ((size_t)(b*SS + kt*64 + key)*NKVH + kvh)*HD + d0;
      *(uint4*)&Klds[key*136 + d0] = *(const uint4*)(kb + gidx);
      uint4 vv = *(const uint4*)(vb + gidx);
      int vb0 = d0*72 + key;
      Vt[vb0      ] = (u16)(vv.x); Vt[vb0 + 72 ] = (u16)(vv.x>>16);
      Vt[vb0 + 144] = (u16)(vv.y); Vt[vb0 + 216] = (u16)(vv.y>>16);
      Vt[vb0 + 288] = (u16)(vv.z); Vt[vb0 + 360] = (u16)(vv.z>>16);
      Vt[vb0 + 432] = (u16)(vv.w); Vt[vb0 + 504] = (u16)(vv.w>>16);
    }
    __syncthreads();
    // S = Q K^T
    f32x4 sacc[2][4];
    #pragma unroll
    for(int m=0;m<2;m++)
      #pragma unroll
      for(int n=0;n<4;n++) sacc[m][n] = (f32x4){0.f,0.f,0.f,0.f};
    #pragma unroll
    for(int nb=0;nb<4;nb++){
      bf16x8 kf[4];
      #pragma unroll
      for(int c=0;c<4;c++)
        kf[c] = *(const bf16x8*)&Klds[(nb*16 + l16)*136 + c*32 + lg*8];
      #pragma unroll
      for(int m=0;m<2;m++)
        #pragma unroll
        for(int c=0;c<4;c++)
          sacc[m][nb] = __builtin_amdgcn_mfma_f32_16x16x32_bf16(qf[m][c], kf[c], sacc[m][nb], 0,0,0);
    }
    // online softmax
    #pragma unroll
    for(int m=0;m<2;m++){
      float alpha[4];
      #pragma unroll
      for(int r=0;r<4;r++){
        float mx = fmaxf(fmaxf(sacc[m][0][r], sacc[m][1][r]), fmaxf(sacc[m][2][r], sacc[m][3][r]));
        mx = fmaxf(mx, __shfl_xor(mx,1));
        mx = fmaxf(mx, __shfl_xor(mx,2));
        mx = fmaxf(mx, __shfl_xor(mx,4));
        mx = fmaxf(mx, __shfl_xor(mx,8));
        float mnew = fmaxf(mrow[m][r], mx);
        alpha[r] = __expf(mrow[m][r] - mnew);
        mrow[m][r] = mnew;
        float rs = 0.f;
        #pragma unroll
        for(int nb=0;nb<4;nb++){
          float p = __expf(sacc[m][nb][r] - mnew);
          sacc[m][nb][r] = p;
          rs += p;
        }
        rs += __shfl_xor(rs,1);
        rs += __shfl_xor(rs,2);
        rs += __shfl_xor(rs,4);
        rs += __shfl_xor(rs,8);
        lrow[m][r] = lrow[m][r]*alpha[r] + rs;
      }
      #pragma unroll
      for(int n=0;n<8;n++)
        #pragma unroll
        for(int r=0;r<4;r++) acc[m][n][r] *= alpha[r];
      #pragma unroll
      for(int nb=0;nb<4;nb++)
        #pragma unroll
        for(int r=0;r<4;r++){
          int prow = m*16 + lg*4 + r;
          Plds[w][prow*72 + nb*16 + l16] = f2bf(sacc[m][nb][r]);
        }
    }
    // O += P V
    #pragma unroll
    for(int c2=0;c2<2;c2++){
      bf16x8 pf[2];
      #pragma unroll
      for(int m=0;m<2;m++)
        pf[m] = *(const bf16x8*)&Plds[w][(m*16 + l16)*72 + c2*32 + lg*8];
      #pragma unroll
      for(int n=0;n<8;n++){
        bf16x8 vf = *(const bf16x8*)&Vt[(n*16 + l16)*72 + c2*32 + lg*8];
        acc[0][n] = __builtin_amdgcn_mfma_f32_16x16x32_bf16(pf[0], vf, acc[0][n], 0,0,0);
        acc[1][n] = __builtin_amdgcn_mfma_f32_16x16x32_bf16(pf[1], vf, acc[1][n], 0,0,0);
      }
    }
    __syncthreads();
  }
  // epilogue: divide by l, add residual, write h (f32)
  #pragma unroll
  for(int m=0;m<2;m++){
    #pragma unroll
    for(int r=0;r<4;r++){
      float inv = 1.0f/lrow[m][r];
      int s = qt*128 + w*32 + m*16 + lg*4 + r;
      size_t base = ((size_t)(b*SS + s))*DIM + h*HD;
      #pragma unroll
      for(int n=0;n<8;n++){
        int d = n*16 + l16;
        out[base + d] = resid[base + d] + acc[m][n][r]*inv;
      }
    }
  }
}

// ---------------- fused FFN: racc[row][16] = (silu(t1 w1_b)+...)path @ w2_a ----------------
// 8 rows/block; never materializes the 4096x5632 activation.
__global__ __launch_bounds__(256,2) void k_ffn(const float* __restrict__ t13,
                                               const float* __restrict__ w1b,
                                               const float* __restrict__ b1,
                                               const float* __restrict__ w3b,
                                               const float* __restrict__ b3,
                                               const float* __restrict__ w2a,
                                               float* __restrict__ racc){
  __shared__ float tl[8][32];
  __shared__ float red[4][128];
  int tid = threadIdx.x;
  int row0 = blockIdx.x*8;
  { int rr = tid>>5, c = tid&31; tl[rr][c] = t13[(size_t)(row0+rr)*32 + c]; }
  __syncthreads();
  float acc[128];
  #pragma unroll
  for(int v=0;v<128;v++) acc[v]=0.f;
  for(int ii=0;ii<INNER/256;ii++){
    int j = tid + 256*ii;
    float w1c[16], w3c[16], w2r[16];
    #pragma unroll
    for(int r=0;r<16;r++){ w1c[r]=w1b[(size_t)r*INNER+j]; w3c[r]=w3b[(size_t)r*INNER+j]; }
    {
      const float4* wp = (const float4*)(w2a + (size_t)j*16);
      #pragma unroll
      for(int q=0;q<4;q++){ float4 t=wp[q]; w2r[q*4]=t.x; w2r[q*4+1]=t.y; w2r[q*4+2]=t.z; w2r[q*4+3]=t.w; }
    }
    float bb1 = b1[j], bb3 = b3[j];
    #pragma unroll
    for(int rr=0;rr<8;rr++){
      float a1=0.f, a3=0.f;
      #pragma unroll
      for(int r=0;r<16;r++){ a1 = fmaf(tl[rr][r], w1c[r], a1); a3 = fmaf(tl[rr][16+r], w3c[r], a3); }
      a1 = a1*0.0625f + bb1;
      a3 = a3*0.0625f + bb3;
      float u = (a1/(1.0f+__expf(-a1))) * a3;
      #pragma unroll
      for(int c=0;c<16;c++) acc[rr*16+c] = fmaf(u, w2r[c], acc[rr*16+c]);
    }
  }
  #pragma unroll
  for(int o=1;o<64;o<<=1){
    #pragma unroll
    for(int v=0;v<128;v++) acc[v] += __shfl_xor(acc[v], o);
  }
  int wv = tid>>6, lane = tid&63;
  if(lane==0){
    #pragma unroll
    for(int v=0;v<128;v++) red[wv][v] = acc[v];
  }
  __syncthreads();
  if(tid<128){
    float sum = red[0][tid]+red[1][tid]+red[2][tid]+red[3][tid];
    racc[(size_t)(row0 + (tid>>4))*16 + (tid&15)] = sum;
  }
}

// ---------------- final: out = h + racc @ w2_b /16 + b2 ----------------
__global__ __launch_bounds__(256) void k_out(const float* __restrict__ racc,
                                             const float* __restrict__ w2b,
                                             const float* __restrict__ b2,
                                             float* __restrict__ io){
  __shared__ u16 wl[16*2048];
  int tid = threadIdx.x;
  for(int ii=0;ii<32;ii++){
    int f4 = tid + 256*ii;
    float4 v = ((const float4*)w2b)[f4];
    uint2 st; st.x = pack2(v.x,v.y); st.y = pack2(v.z,v.w);
    *(uint2*)&wl[f4*4] = st;
  }
  __syncthreads();
  int j0 = tid*8;
  float b2v[8];
  #pragma unroll
  for(int e=0;e<8;e++) b2v[e] = b2[j0+e];
  for(int rr=0;rr<16;rr++){
    int row = blockIdx.x*16 + rr;
    float rc[16];
    #pragma unroll
    for(int r=0;r<16;r++) rc[r] = racc[(size_t)row*16 + r];
    float pre[8];
    #pragma unroll
    for(int e=0;e<8;e++) pre[e]=0.f;
    #pragma unroll
    for(int r=0;r<16;r++){
      bf16x8 wv = *(const bf16x8*)&wl[r*2048 + j0];
      #pragma unroll
      for(int e=0;e<8;e++) pre[e] = fmaf(rc[r], (float)wv[e], pre[e]);
    }
    float* op = io + (size_t)row*DIM + j0;
    float4 h0 = ((const float4*)op)[0];
    float4 h1 = ((const float4*)op)[1];
    float4 o0, o1;
    o0.x = h0.x + pre[0]*0.0625f + b2v[0];
    o0.y = h0.y + pre[1]*0.0625f + b2v[1];
    o0.z = h0.z + pre[2]*0.0625f + b2v[2];
    o0.w = h0.w + pre[3]*0.0625f + b2v[3];
    o1.x = h1.x + pre[4]*0.0625f + b2v[4];
    o1.y = h1.y + pre[5]*0.0625f + b2v[5];
    o1.z = h1.z + pre[6]*0.0625f + b2v[6];
    o1.w = h1.w + pre[7]*0.0625f + b2v[7];
    ((float4*)op)[0] = o0;
    ((float4*)op)[1] = o1;
  }
}

extern "C" void kernel_launch(void* const* d_in, const int* in_sizes, int n_in,
                              void* d_out, int out_size, void* d_ws, size_t ws_size,
                              hipStream_t stream){
  const float* hidden = (const float*)d_in[0];
  // d_in[1] attention_mask: all-true, no-op in reference -> ignored
  const float* cosT = (const float*)d_in[2];
  const float* sinT = (const float*)d_in[3];
  const float* wq_a = (const float*)d_in[4];
  const float* wq_b = (const float*)d_in[5];
  const float* bq   = (const float*)d_in[6];
  const float* wk_a = (const float*)d_in[7];
  const float* wk_b = (const float*)d_in[8];
  const float* bk   = (const float*)d_in[9];
  const float* wv_a = (const float*)d_in[10];
  const float* wv_b = (const float*)d_in[11];
  const float* bv   = (const float*)d_in[12];
  const float* nqw  = (const float*)d_in[13];
  const float* nqb  = (const float*)d_in[14];
  const float* nkw  = (const float*)d_in[15];
  const float* nkb  = (const float*)d_in[16];
  const float* w1a  = (const float*)d_in[17];
  const float* w1b  = (const float*)d_in[18];
  const float* b1   = (const float*)d_in[19];
  const float* w3a  = (const float*)d_in[20];
  const float* w3b  = (const float*)d_in[21];
  const float* b3   = (const float*)d_in[22];
  const float* w2a  = (const float*)d_in[23];
  const float* w2b  = (const float*)d_in[24];
  const float* b2   = (const float*)d_in[25];
  const float* normw  = (const float*)d_in[26];
  const float* fnormw = (const float*)d_in[27];
  float* out = (float*)d_out;

  // ws layout (~35.1 MB): bufA serves nh -> (dead) and later nf; qb is separate
  char* p = (char*)d_ws;
  u16* bufA = (u16*)p; p += (size_t)NROWS*DIM*2;       // nh, then nf (16.78 MB)
  u16* qbuf = (u16*)p; p += (size_t)NROWS*DIM*2;       // q bf16 (16.78 MB)... wait
  u16* kbuf = (u16*)p; p += (size_t)NROWS*1024*2;      // 8.39 MB
  u16* vbuf = (u16*)p; p += (size_t)NROWS*1024*2;      // 8.39 MB
  float* xa   = (float*)p; p += (size_t)NROWS*48*4;
  float* t13  = (float*)p; p += (size_t)NROWS*32*4;
  float* racc = (float*)p; p += (size_t)NROWS*16*4;

  k_rms<<<NROWS,256,0,stream>>>(hidden, normw, bufA);                       // nh
  k_loraA<3><<<NROWS/16,256,0,stream>>>(bufA, wq_a, wk_a, wv_a, xa);
  k_qb <<<NROWS/16,256,0,stream>>>(xa, wq_b, bq, nqw, nqb, cosT, sinT, qbuf);
  k_kvb<<<NROWS/16,256,0,stream>>>(xa, wk_b, bk, nkw, nkb, wv_b, bv, cosT, sinT, kbuf, vbuf);
  k_attn<<<512,256,0,stream>>>(qbuf, kbuf, vbuf, hidden, out);              // out = h
  k_rms<<<NROWS,256,0,stream>>>(out, fnormw, bufA);                         // nf
  k_loraA<2><<<NROWS/16,256,0,stream>>>(bufA, w1a, w3a, nullptr, t13);
  k_ffn<<<NROWS/8,256,0,stream>>>(t13, w1b, b1, w3b, b3, w2a, racc);
  k_out<<<NROWS/16,256,0,stream>>>(racc, w2b, b2, out);
}

// Round 2
// 765.151 us; speedup vs baseline: 1.6471x; 1.6471x over previous
//
#include <hip/hip_runtime.h>
#include <math.h>

typedef unsigned short u16;
typedef unsigned int u32;
typedef __bf16 bf16x8 __attribute__((ext_vector_type(8)));
typedef __bf16 bf16x4 __attribute__((ext_vector_type(4)));
typedef float f32x4 __attribute__((ext_vector_type(4)));

#define DIM 2048
#define NHEADS 16
#define NKVH 8
#define HD 128
#define RANK 16
#define INNER 5632
#define BB 2
#define SS 2048
#define NROWS (BB*SS)
#define EPS 1e-5f
#define QSCALE 0.08838834764831845f  /* 1/sqrt(128) */

__device__ inline float bf2f(u16 u){ u32 x = ((u32)u)<<16; float f; __builtin_memcpy(&f,&x,4); return f; }
__device__ inline u16 f2bf(float f){ u32 u; __builtin_memcpy(&u,&f,4); u32 r = u + 0x7fffu + ((u>>16)&1u); return (u16)(r>>16); }
__device__ inline u32 pack2(float a, float b){ return (u32)f2bf(a) | ((u32)f2bf(b)<<16); }

__device__ inline float blockReduceSum(float v){
  __shared__ float r[4];
  #pragma unroll
  for(int o=1;o<64;o<<=1) v += __shfl_xor(v, o);
  int wv = threadIdx.x>>6;
  __syncthreads();
  if((threadIdx.x&63)==0) r[wv] = v;
  __syncthreads();
  return r[0]+r[1]+r[2]+r[3];
}

__device__ inline float2 blockReduceSum2(float a, float b){
  __shared__ float ra[4], rb[4];
  #pragma unroll
  for(int o=1;o<64;o<<=1){ a += __shfl_xor(a, o); b += __shfl_xor(b, o); }
  int wv = threadIdx.x>>6;
  __syncthreads();
  if((threadIdx.x&63)==0){ ra[wv]=a; rb[wv]=b; }
  __syncthreads();
  return make_float2(ra[0]+ra[1]+ra[2]+ra[3], rb[0]+rb[1]+rb[2]+rb[3]);
}

// ---------------- RMSNorm: f32 in -> bf16 out (row = block) ----------------
__global__ __launch_bounds__(256) void k_rms(const float* __restrict__ x,
                                             const float* __restrict__ w,
                                             u16* __restrict__ out){
  size_t base = (size_t)blockIdx.x*DIM;
  int tid = threadIdx.x;
  float4 v0 = ((const float4*)(x+base))[tid*2];
  float4 v1 = ((const float4*)(x+base))[tid*2+1];
  float ss = v0.x*v0.x+v0.y*v0.y+v0.z*v0.z+v0.w*v0.w
           + v1.x*v1.x+v1.y*v1.y+v1.z*v1.z+v1.w*v1.w;
  ss = blockReduceSum(ss);
  float rstd = rsqrtf(ss*(1.0f/DIM) + EPS);
  float4 w0 = ((const float4*)w)[tid*2];
  float4 w1 = ((const float4*)w)[tid*2+1];
  uint4 st;
  st.x = pack2(v0.x*w0.x*rstd, v0.y*w0.y*rstd);
  st.y = pack2(v0.z*w0.z*rstd, v0.w*w0.w*rstd);
  st.z = pack2(v1.x*w1.x*rstd, v1.y*w1.y*rstd);
  st.w = pack2(v1.z*w1.z*rstd, v1.w*w1.w*rstd);
  *(uint4*)&out[base + tid*8] = st;
}

// ---------------- LoRA-A: out[M][NM*16] = Xbf16[M][DIM] @ [A0|A1|A2] ----------------
// 16 rows/block, 16-way k-split per row, shfl reduce. X loads vectorized bf16x8.
template<int NM>
__global__ __launch_bounds__(256) void k_loraA(const u16* __restrict__ X,
                                               const float* __restrict__ A0,
                                               const float* __restrict__ A1,
                                               const float* __restrict__ A2,
                                               float* __restrict__ out){
  constexpr int N = NM*16;
  int tid = threadIdx.x;
  int row = blockIdx.x*16 + (tid>>4);
  int ks  = tid&15;
  float acc[N];
  #pragma unroll
  for(int c=0;c<N;c++) acc[c]=0.f;
  const u16* xp = X + (size_t)row*DIM + ks*128;
  for(int i8=0;i8<16;i8++){
    bf16x8 xv8 = *(const bf16x8*)(xp + i8*8);
    #pragma unroll
    for(int e=0;e<8;e++){
      int k = ks*128 + i8*8 + e;
      float xv = (float)xv8[e];
      {
        const float4* a = (const float4*)(A0 + (size_t)k*16);
        #pragma unroll
        for(int q=0;q<4;q++){ float4 t=a[q];
          acc[q*4+0]=fmaf(xv,t.x,acc[q*4+0]); acc[q*4+1]=fmaf(xv,t.y,acc[q*4+1]);
          acc[q*4+2]=fmaf(xv,t.z,acc[q*4+2]); acc[q*4+3]=fmaf(xv,t.w,acc[q*4+3]); }
      }
      if constexpr (NM>1){
        const float4* a = (const float4*)(A1 + (size_t)k*16);
        #pragma unroll
        for(int q=0;q<4;q++){ float4 t=a[q];
          acc[16+q*4+0]=fmaf(xv,t.x,acc[16+q*4+0]); acc[16+q*4+1]=fmaf(xv,t.y,acc[16+q*4+1]);
          acc[16+q*4+2]=fmaf(xv,t.z,acc[16+q*4+2]); acc[16+q*4+3]=fmaf(xv,t.w,acc[16+q*4+3]); }
      }
      if constexpr (NM>2){
        const float4* a = (const float4*)(A2 + (size_t)k*16);
        #pragma unroll
        for(int q=0;q<4;q++){ float4 t=a[q];
          acc[32+q*4+0]=fmaf(xv,t.x,acc[32+q*4+0]); acc[32+q*4+1]=fmaf(xv,t.y,acc[32+q*4+1]);
          acc[32+q*4+2]=fmaf(xv,t.z,acc[32+q*4+2]); acc[32+q*4+3]=fmaf(xv,t.w,acc[32+q*4+3]); }
      }
    }
  }
  #pragma unroll
  for(int o=1;o<16;o<<=1){
    #pragma unroll
    for(int c=0;c<N;c++) acc[c] += __shfl_xor(acc[c], o);
  }
  if(ks==0){
    #pragma unroll
    for(int c=0;c<N;c++) out[(size_t)row*N + c] = acc[c];
  }
}

// ---------------- Q path: LoRA-B + LayerNorm + RoPE + scale -> bf16 ----------------
__global__ __launch_bounds__(256) void k_qb(const float* __restrict__ xa,
                                            const float* __restrict__ wqb,
                                            const float* __restrict__ bq,
                                            const float* __restrict__ nqw,
                                            const float* __restrict__ nqb,
                                            const float* __restrict__ cosT,
                                            const float* __restrict__ sinT,
                                            u16* __restrict__ qout){
  __shared__ u16 wl[16*2048];  // 64 KB, bf16 weights
  int tid = threadIdx.x;
  for(int ii=0;ii<32;ii++){
    int f4 = tid + 256*ii;
    float4 v = ((const float4*)wqb)[f4];
    uint2 st; st.x = pack2(v.x,v.y); st.y = pack2(v.z,v.w);
    *(uint2*)&wl[f4*4] = st;
  }
  __syncthreads();
  int j0 = tid*8;
  float bqv[8], nwv[8], nbv[8];
  #pragma unroll
  for(int e=0;e<8;e++){ bqv[e]=bq[j0+e]; nwv[e]=nqw[j0+e]; nbv[e]=nqb[j0+e]; }
  int i0 = (j0&127)>>1;
  for(int rr=0;rr<16;rr++){
    int row = blockIdx.x*16 + rr;
    float xq[16];
    #pragma unroll
    for(int r=0;r<16;r++) xq[r] = xa[(size_t)row*48 + r];
    float pre[8];
    #pragma unroll
    for(int e=0;e<8;e++) pre[e]=0.f;
    #pragma unroll
    for(int r=0;r<16;r++){
      bf16x8 wv = *(const bf16x8*)&wl[r*2048 + j0];
      #pragma unroll
      for(int e=0;e<8;e++) pre[e] = fmaf(xq[r], (float)wv[e], pre[e]);
    }
    #pragma unroll
    for(int e=0;e<8;e++) pre[e] = pre[e]*0.0625f + bqv[e];
    float s=0.f, sq=0.f;
    #pragma unroll
    for(int e=0;e<8;e++){ s+=pre[e]; sq+=pre[e]*pre[e]; }
    float2 red = blockReduceSum2(s, sq);
    float mu = red.x*(1.0f/DIM);
    float var = red.y*(1.0f/DIM) - mu*mu;
    float rstd = rsqrtf(var + EPS);
    float qn[8];
    #pragma unroll
    for(int e=0;e<8;e++) qn[e] = (pre[e]-mu)*rstd*nwv[e] + nbv[e];
    int spos = row & (SS-1);
    const float* cp = cosT + spos*64;
    const float* sp = sinT + spos*64;
    uint4 st;
    u32 pk[4];
    #pragma unroll
    for(int p=0;p<4;p++){
      float c = cp[i0+p], sn = sp[i0+p];
      float x0 = qn[2*p], x1 = qn[2*p+1];
      pk[p] = pack2((x0*c - x1*sn)*QSCALE, (x0*sn + x1*c)*QSCALE);
    }
    st.x=pk[0]; st.y=pk[1]; st.z=pk[2]; st.w=pk[3];
    *(uint4*)&qout[(size_t)row*2048 + j0] = st;
  }
}

// ---------------- K/V path: LoRA-B (+LN+RoPE for K) -> bf16 ----------------
__global__ __launch_bounds__(256) void k_kvb(const float* __restrict__ xa,
                                             const float* __restrict__ wkb,
                                             const float* __restrict__ bk,
                                             const float* __restrict__ nkw,
                                             const float* __restrict__ nkb,
                                             const float* __restrict__ wvb,
                                             const float* __restrict__ bv,
                                             const float* __restrict__ cosT,
                                             const float* __restrict__ sinT,
                                             u16* __restrict__ kout,
                                             u16* __restrict__ vout){
  __shared__ u16 wl[2*16*1024];  // 64 KB: [0,16K)=wk_b, [16K,32K)=wv_b
  int tid = threadIdx.x;
  for(int ii=0;ii<32;ii++){
    int f4 = tid + 256*ii;
    float4 v = (f4 < 4096) ? ((const float4*)wkb)[f4] : ((const float4*)wvb)[f4-4096];
    uint2 st; st.x = pack2(v.x,v.y); st.y = pack2(v.z,v.w);
    *(uint2*)&wl[f4*4] = st;
  }
  __syncthreads();
  int j0 = tid*4;
  float bkv[4], nwv[4], nbv[4], bvv[4];
  #pragma unroll
  for(int e=0;e<4;e++){ bkv[e]=bk[j0+e]; nwv[e]=nkw[j0+e]; nbv[e]=nkb[j0+e]; bvv[e]=bv[j0+e]; }
  int i0 = (j0&127)>>1;
  for(int rr=0;rr<16;rr++){
    int row = blockIdx.x*16 + rr;
    float xk[16], xv[16];
    #pragma unroll
    for(int r=0;r<16;r++){ xk[r]=xa[(size_t)row*48+16+r]; xv[r]=xa[(size_t)row*48+32+r]; }
    float pk_[4], pv_[4];
    #pragma unroll
    for(int e=0;e<4;e++){ pk_[e]=0.f; pv_[e]=0.f; }
    #pragma unroll
    for(int r=0;r<16;r++){
      bf16x4 wk4 = *(const bf16x4*)&wl[r*1024 + j0];
      bf16x4 wv4 = *(const bf16x4*)&wl[16384 + r*1024 + j0];
      #pragma unroll
      for(int e=0;e<4;e++){ pk_[e]=fmaf(xk[r],(float)wk4[e],pk_[e]); pv_[e]=fmaf(xv[r],(float)wv4[e],pv_[e]); }
    }
    #pragma unroll
    for(int e=0;e<4;e++){ pk_[e]=pk_[e]*0.0625f + bkv[e]; pv_[e]=pv_[e]*0.0625f + bvv[e]; }
    float s=0.f, sq=0.f;
    #pragma unroll
    for(int e=0;e<4;e++){ s+=pk_[e]; sq+=pk_[e]*pk_[e]; }
    float2 red = blockReduceSum2(s, sq);
    float mu = red.x*(1.0f/1024.0f);
    float var = red.y*(1.0f/1024.0f) - mu*mu;
    float rstd = rsqrtf(var + EPS);
    float kn[4];
    #pragma unroll
    for(int e=0;e<4;e++) kn[e] = (pk_[e]-mu)*rstd*nwv[e] + nbv[e];
    int spos = row & (SS-1);
    const float* cp = cosT + spos*64;
    const float* sp = sinT + spos*64;
    uint2 stk;
    { float c=cp[i0],   sn=sp[i0];   stk.x = pack2(kn[0]*c - kn[1]*sn, kn[0]*sn + kn[1]*c); }
    { float c=cp[i0+1], sn=sp[i0+1]; stk.y = pack2(kn[2]*c - kn[3]*sn, kn[2]*sn + kn[3]*c); }
    *(uint2*)&kout[(size_t)row*1024 + j0] = stk;
    uint2 stv; stv.x = pack2(pv_[0],pv_[1]); stv.y = pack2(pv_[2],pv_[3]);
    *(uint2*)&vout[(size_t)row*1024 + j0] = stv;
  }
}

// ---------------- Flash attention + residual add -> d_out (f32 h) ----------------
// grid 512 = b(2) x h(16) x qtile(16); block 256 = 4 waves x 32 q-rows each.
__global__ __launch_bounds__(256,2) void k_attn(const u16* __restrict__ qb,
                                                const u16* __restrict__ kb,
                                                const u16* __restrict__ vb,
                                                const float* __restrict__ resid,
                                                float* __restrict__ out){
  __shared__ u16 Klds[64*136];     // [key][d], pad 136 -> 2-way-max conflicts
  __shared__ u16 Vt[128*72];       // [d][key], pad 72
  __shared__ u16 Plds[4][32*72];   // per-wave P, [qrow][key], pad 72
  int bid = blockIdx.x;
  int qt = bid & 15;
  int h  = (bid>>4) & 15;
  int b  = bid>>8;
  int kvh = h>>1;
  int tid = threadIdx.x;
  int w = tid>>6, lane = tid&63;
  int lg = lane>>4, l16 = lane&15;

  bf16x8 qf[2][4];
  #pragma unroll
  for(int m=0;m<2;m++){
    int s = qt*128 + w*32 + m*16 + l16;
    const u16* qp = qb + ((size_t)(b*SS + s))*DIM + h*HD + lg*8;
    qf[m][0] = *(const bf16x8*)(qp);
    qf[m][1] = *(const bf16x8*)(qp+32);
    qf[m][2] = *(const bf16x8*)(qp+64);
    qf[m][3] = *(const bf16x8*)(qp+96);
  }
  f32x4 acc[2][8];
  #pragma unroll
  for(int m=0;m<2;m++)
    #pragma unroll
    for(int n=0;n<8;n++) acc[m][n] = (f32x4){0.f,0.f,0.f,0.f};
  float mrow[2][4], lrow[2][4];
  #pragma unroll
  for(int m=0;m<2;m++)
    #pragma unroll
    for(int r=0;r<4;r++){ mrow[m][r] = -INFINITY; lrow[m][r] = 0.f; }

  for(int kt=0; kt<SS/64; kt++){
    // stage K [key][d] and V^T [d][key]
    #pragma unroll
    for(int jj=0;jj<4;jj++){
      int mi = tid + 256*jj;
      int key = mi>>4, d0 = (mi&15)*8;
      size_t gidx = ((size_t)(b*SS + kt*64 + key)*NKVH + kvh)*HD + d0;
      *(uint4*)&Klds[key*136 + d0] = *(const uint4*)(kb + gidx);
      uint4 vv = *(const uint4*)(vb + gidx);
      int vb0 = d0*72 + key;
      Vt[vb0      ] = (u16)(vv.x); Vt[vb0 + 72 ] = (u16)(vv.x>>16);
      Vt[vb0 + 144] = (u16)(vv.y); Vt[vb0 + 216] = (u16)(vv.y>>16);
      Vt[vb0 + 288] = (u16)(vv.z); Vt[vb0 + 360] = (u16)(vv.z>>16);
      Vt[vb0 + 432] = (u16)(vv.w); Vt[vb0 + 504] = (u16)(vv.w>>16);
    }
    __syncthreads();
    // S = Q K^T
    f32x4 sacc[2][4];
    #pragma unroll
    for(int m=0;m<2;m++)
      #pragma unroll
      for(int n=0;n<4;n++) sacc[m][n] = (f32x4){0.f,0.f,0.f,0.f};
    #pragma unroll
    for(int nb=0;nb<4;nb++){
      bf16x8 kf[4];
      #pragma unroll
      for(int c=0;c<4;c++)
        kf[c] = *(const bf16x8*)&Klds[(nb*16 + l16)*136 + c*32 + lg*8];
      #pragma unroll
      for(int m=0;m<2;m++)
        #pragma unroll
        for(int c=0;c<4;c++)
          sacc[m][nb] = __builtin_amdgcn_mfma_f32_16x16x32_bf16(qf[m][c], kf[c], sacc[m][nb], 0,0,0);
    }
    // online softmax
    #pragma unroll
    for(int m=0;m<2;m++){
      float alpha[4];
      #pragma unroll
      for(int r=0;r<4;r++){
        float mx = fmaxf(fmaxf(sacc[m][0][r], sacc[m][1][r]), fmaxf(sacc[m][2][r], sacc[m][3][r]));
        mx = fmaxf(mx, __shfl_xor(mx,1));
        mx = fmaxf(mx, __shfl_xor(mx,2));
        mx = fmaxf(mx, __shfl_xor(mx,4));
        mx = fmaxf(mx, __shfl_xor(mx,8));
        float mnew = fmaxf(mrow[m][r], mx);
        alpha[r] = __expf(mrow[m][r] - mnew);
        mrow[m][r] = mnew;
        float rs = 0.f;
        #pragma unroll
        for(int nb=0;nb<4;nb++){
          float p = __expf(sacc[m][nb][r] - mnew);
          sacc[m][nb][r] = p;
          rs += p;
        }
        rs += __shfl_xor(rs,1);
        rs += __shfl_xor(rs,2);
        rs += __shfl_xor(rs,4);
        rs += __shfl_xor(rs,8);
        lrow[m][r] = lrow[m][r]*alpha[r] + rs;
      }
      #pragma unroll
      for(int n=0;n<8;n++)
        #pragma unroll
        for(int r=0;r<4;r++) acc[m][n][r] *= alpha[r];
      #pragma unroll
      for(int nb=0;nb<4;nb++)
        #pragma unroll
        for(int r=0;r<4;r++){
          int prow = m*16 + lg*4 + r;
          Plds[w][prow*72 + nb*16 + l16] = f2bf(sacc[m][nb][r]);
        }
    }
    // O += P V
    #pragma unroll
    for(int c2=0;c2<2;c2++){
      bf16x8 pf[2];
      #pragma unroll
      for(int m=0;m<2;m++)
        pf[m] = *(const bf16x8*)&Plds[w][(m*16 + l16)*72 + c2*32 + lg*8];
      #pragma unroll
      for(int n=0;n<8;n++){
        bf16x8 vf = *(const bf16x8*)&Vt[(n*16 + l16)*72 + c2*32 + lg*8];
        acc[0][n] = __builtin_amdgcn_mfma_f32_16x16x32_bf16(pf[0], vf, acc[0][n], 0,0,0);
        acc[1][n] = __builtin_amdgcn_mfma_f32_16x16x32_bf16(pf[1], vf, acc[1][n], 0,0,0);
      }
    }
    __syncthreads();
  }
  // epilogue: divide by l, add residual, write h (f32)
  #pragma unroll
  for(int m=0;m<2;m++){
    #pragma unroll
    for(int r=0;r<4;r++){
      float inv = 1.0f/lrow[m][r];
      int s = qt*128 + w*32 + m*16 + lg*4 + r;
      size_t base = ((size_t)(b*SS + s))*DIM + h*HD;
      #pragma unroll
      for(int n=0;n<8;n++){
        int d = n*16 + l16;
        out[base + d] = resid[base + d] + acc[m][n][r]*inv;
      }
    }
  }
}

// ---------------- fused FFN: racc[row][16] = silu/gate path @ w2_a ----------------
// 4 rows/block, acc[64] per thread (fits registers, no scratch spill).
__global__ __launch_bounds__(256) void k_ffn(const float* __restrict__ t13,
                                             const float* __restrict__ w1b,
                                             const float* __restrict__ b1,
                                             const float* __restrict__ w3b,
                                             const float* __restrict__ b3,
                                             const float* __restrict__ w2a,
                                             float* __restrict__ racc){
  __shared__ float tl[4][32];
  __shared__ float red[4][64];
  int tid = threadIdx.x;
  int row0 = blockIdx.x*4;
  if(tid<128) tl[tid>>5][tid&31] = t13[(size_t)row0*32 + tid];
  __syncthreads();
  float acc[64];
  #pragma unroll
  for(int v=0;v<64;v++) acc[v]=0.f;
  for(int ii=0;ii<INNER/256;ii++){
    int j = tid + 256*ii;
    float w1c[16], w3c[16], w2r[16];
    #pragma unroll
    for(int r=0;r<16;r++){ w1c[r]=w1b[(size_t)r*INNER+j]; w3c[r]=w3b[(size_t)r*INNER+j]; }
    {
      const float4* wp = (const float4*)(w2a + (size_t)j*16);
      #pragma unroll
      for(int q=0;q<4;q++){ float4 t=wp[q]; w2r[q*4]=t.x; w2r[q*4+1]=t.y; w2r[q*4+2]=t.z; w2r[q*4+3]=t.w; }
    }
    float bb1 = b1[j], bb3 = b3[j];
    #pragma unroll
    for(int rr=0;rr<4;rr++){
      float a1=0.f, a3=0.f;
      #pragma unroll
      for(int r=0;r<16;r++){ a1 = fmaf(tl[rr][r], w1c[r], a1); a3 = fmaf(tl[rr][16+r], w3c[r], a3); }
      a1 = a1*0.0625f + bb1;
      a3 = a3*0.0625f + bb3;
      float u = (a1/(1.0f+__expf(-a1))) * a3;
      #pragma unroll
      for(int c=0;c<16;c++) acc[rr*16+c] = fmaf(u, w2r[c], acc[rr*16+c]);
    }
  }
  #pragma unroll
  for(int o=1;o<64;o<<=1){
    #pragma unroll
    for(int v=0;v<64;v++) acc[v] += __shfl_xor(acc[v], o);
  }
  int wv = tid>>6, lane = tid&63;
  if(lane==0){
    #pragma unroll
    for(int v=0;v<64;v++) red[wv][v] = acc[v];
  }
  __syncthreads();
  if(tid<64){
    float sum = red[0][tid]+red[1][tid]+red[2][tid]+red[3][tid];
    racc[(size_t)(row0 + (tid>>4))*16 + (tid&15)] = sum;
  }
}

// ---------------- final: out = h + racc @ w2_b /16 + b2 ----------------
__global__ __launch_bounds__(256) void k_out(const float* __restrict__ racc,
                                             const float* __restrict__ w2b,
                                             const float* __restrict__ b2,
                                             float* __restrict__ io){
  __shared__ u16 wl[16*2048];
  int tid = threadIdx.x;
  for(int ii=0;ii<32;ii++){
    int f4 = tid + 256*ii;
    float4 v = ((const float4*)w2b)[f4];
    uint2 st; st.x = pack2(v.x,v.y); st.y = pack2(v.z,v.w);
    *(uint2*)&wl[f4*4] = st;
  }
  __syncthreads();
  int j0 = tid*8;
  float b2v[8];
  #pragma unroll
  for(int e=0;e<8;e++) b2v[e] = b2[j0+e];
  for(int rr=0;rr<16;rr++){
    int row = blockIdx.x*16 + rr;
    float rc[16];
    #pragma unroll
    for(int r=0;r<16;r++) rc[r] = racc[(size_t)row*16 + r];
    float pre[8];
    #pragma unroll
    for(int e=0;e<8;e++) pre[e]=0.f;
    #pragma unroll
    for(int r=0;r<16;r++){
      bf16x8 wv = *(const bf16x8*)&wl[r*2048 + j0];
      #pragma unroll
      for(int e=0;e<8;e++) pre[e] = fmaf(rc[r], (float)wv[e], pre[e]);
    }
    float* op = io + (size_t)row*DIM + j0;
    float4 h0 = ((const float4*)op)[0];
    float4 h1 = ((const float4*)op)[1];
    float4 o0, o1;
    o0.x = h0.x + pre[0]*0.0625f + b2v[0];
    o0.y = h0.y + pre[1]*0.0625f + b2v[1];
    o0.z = h0.z + pre[2]*0.0625f + b2v[2];
    o0.w = h0.w + pre[3]*0.0625f + b2v[3];
    o1.x = h1.x + pre[4]*0.0625f + b2v[4];
    o1.y = h1.y + pre[5]*0.0625f + b2v[5];
    o1.z = h1.z + pre[6]*0.0625f + b2v[6];
    o1.w = h1.w + pre[7]*0.0625f + b2v[7];
    ((float4*)op)[0] = o0;
    ((float4*)op)[1] = o1;
  }
}

extern "C" void kernel_launch(void* const* d_in, const int* in_sizes, int n_in,
                              void* d_out, int out_size, void* d_ws, size_t ws_size,
                              hipStream_t stream){
  const float* hidden = (const float*)d_in[0];
  // d_in[1] attention_mask: all-true, no-op in reference -> ignored
  const float* cosT = (const float*)d_in[2];
  const float* sinT = (const float*)d_in[3];
  const float* wq_a = (const float*)d_in[4];
  const float* wq_b = (const float*)d_in[5];
  const float* bq   = (const float*)d_in[6];
  const float* wk_a = (const float*)d_in[7];
  const float* wk_b = (const float*)d_in[8];
  const float* bk   = (const float*)d_in[9];
  const float* wv_a = (const float*)d_in[10];
  const float* wv_b = (const float*)d_in[11];
  const float* bv   = (const float*)d_in[12];
  const float* nqw  = (const float*)d_in[13];
  const float* nqb  = (const float*)d_in[14];
  const float* nkw  = (const float*)d_in[15];
  const float* nkb  = (const float*)d_in[16];
  const float* w1a  = (const float*)d_in[17];
  const float* w1b  = (const float*)d_in[18];
  const float* b1   = (const float*)d_in[19];
  const float* w3a  = (const float*)d_in[20];
  const float* w3b  = (const float*)d_in[21];
  const float* b3   = (const float*)d_in[22];
  const float* w2a  = (const float*)d_in[23];
  const float* w2b  = (const float*)d_in[24];
  const float* b2   = (const float*)d_in[25];
  const float* normw  = (const float*)d_in[26];
  const float* fnormw = (const float*)d_in[27];
  float* out = (float*)d_out;

  // ws layout (~35.1 MB)
  char* p = (char*)d_ws;
  u16* bufA = (u16*)p; p += (size_t)NROWS*DIM*2;       // nh, then nf
  u16* qbuf = (u16*)p; p += (size_t)NROWS*DIM*2;       // q bf16
  u16* kbuf = (u16*)p; p += (size_t)NROWS*1024*2;
  u16* vbuf = (u16*)p; p += (size_t)NROWS*1024*2;
  float* xa   = (float*)p; p += (size_t)NROWS*48*4;
  float* t13  = (float*)p; p += (size_t)NROWS*32*4;
  float* racc = (float*)p; p += (size_t)NROWS*16*4;

  k_rms<<<NROWS,256,0,stream>>>(hidden, normw, bufA);                       // nh
  k_loraA<3><<<NROWS/16,256,0,stream>>>(bufA, wq_a, wk_a, wv_a, xa);
  k_qb <<<NROWS/16,256,0,stream>>>(xa, wq_b, bq, nqw, nqb, cosT, sinT, qbuf);
  k_kvb<<<NROWS/16,256,0,stream>>>(xa, wk_b, bk, nkw, nkb, wv_b, bv, cosT, sinT, kbuf, vbuf);
  k_attn<<<512,256,0,stream>>>(qbuf, kbuf, vbuf, hidden, out);              // out = h
  k_rms<<<NROWS,256,0,stream>>>(out, fnormw, bufA);                         // nf
  k_loraA<2><<<NROWS/16,256,0,stream>>>(bufA, w1a, w3a, nullptr, t13);
  k_ffn<<<NROWS/4,256,0,stream>>>(t13, w1b, b1, w3b, b3, w2a, racc);
  k_out<<<NROWS/16,256,0,stream>>>(racc, w2b, b2, out);
}

// Round 3
// 546.783 us; speedup vs baseline: 2.3049x; 1.3994x over previous
//
#include <hip/hip_runtime.h>
#include <math.h>

typedef unsigned short u16;
typedef unsigned int u32;
typedef __bf16 bf16x8 __attribute__((ext_vector_type(8)));
typedef __bf16 bf16x4 __attribute__((ext_vector_type(4)));
typedef float f32x4 __attribute__((ext_vector_type(4)));

#define DIM 2048
#define NHEADS 16
#define NKVH 8
#define HD 128
#define RANK 16
#define INNER 5632
#define BB 2
#define SS 2048
#define NROWS (BB*SS)
#define EPS 1e-5f
#define QSCALE 0.08838834764831845f  /* 1/sqrt(128) */

__device__ inline float bf2f(u16 u){ u32 x = ((u32)u)<<16; float f; __builtin_memcpy(&f,&x,4); return f; }
__device__ inline u16 f2bf(float f){ u32 u; __builtin_memcpy(&u,&f,4); u32 r = u + 0x7fffu + ((u>>16)&1u); return (u16)(r>>16); }
__device__ inline u32 pack2(float a, float b){ return (u32)f2bf(a) | ((u32)f2bf(b)<<16); }

__device__ inline float blockReduceSum(float v){
  __shared__ float r[4];
  #pragma unroll
  for(int o=1;o<64;o<<=1) v += __shfl_xor(v, o);
  int wv = threadIdx.x>>6;
  __syncthreads();
  if((threadIdx.x&63)==0) r[wv] = v;
  __syncthreads();
  return r[0]+r[1]+r[2]+r[3];
}

__device__ inline float2 blockReduceSum2(float a, float b){
  __shared__ float ra[4], rb[4];
  #pragma unroll
  for(int o=1;o<64;o<<=1){ a += __shfl_xor(a, o); b += __shfl_xor(b, o); }
  int wv = threadIdx.x>>6;
  __syncthreads();
  if((threadIdx.x&63)==0){ ra[wv]=a; rb[wv]=b; }
  __syncthreads();
  return make_float2(ra[0]+ra[1]+ra[2]+ra[3], rb[0]+rb[1]+rb[2]+rb[3]);
}

// ---------------- RMSNorm: f32 in -> bf16 out (row = block) ----------------
__global__ __launch_bounds__(256) void k_rms(const float* __restrict__ x,
                                             const float* __restrict__ w,
                                             u16* __restrict__ out){
  size_t base = (size_t)blockIdx.x*DIM;
  int tid = threadIdx.x;
  float4 v0 = ((const float4*)(x+base))[tid*2];
  float4 v1 = ((const float4*)(x+base))[tid*2+1];
  float ss = v0.x*v0.x+v0.y*v0.y+v0.z*v0.z+v0.w*v0.w
           + v1.x*v1.x+v1.y*v1.y+v1.z*v1.z+v1.w*v1.w;
  ss = blockReduceSum(ss);
  float rstd = rsqrtf(ss*(1.0f/DIM) + EPS);
  float4 w0 = ((const float4*)w)[tid*2];
  float4 w1 = ((const float4*)w)[tid*2+1];
  uint4 st;
  st.x = pack2(v0.x*w0.x*rstd, v0.y*w0.y*rstd);
  st.y = pack2(v0.z*w0.z*rstd, v0.w*w0.w*rstd);
  st.z = pack2(v1.x*w1.x*rstd, v1.y*w1.y*rstd);
  st.w = pack2(v1.z*w1.z*rstd, v1.w*w1.w*rstd);
  *(uint4*)&out[base + tid*8] = st;
}

// ---------------- LoRA-A: 4 rows/thread amortizes A loads; NMAT matrices per launch ----
// block 256 = 16 ksplit x 16 rowgroups; 64 rows/block/mat; grid = NMAT*64.
template<int NMAT>
__global__ __launch_bounds__(256) void k_loraAm(const u16* __restrict__ X,
                                                const float* __restrict__ A0,
                                                const float* __restrict__ A1,
                                                const float* __restrict__ A2,
                                                float* __restrict__ out){
  constexpr int LDO = NMAT*16;
  int mat = blockIdx.x >> 6;
  int blk = blockIdx.x & 63;
  const float* A = (mat==0) ? A0 : ((NMAT>2 && mat==2) ? A2 : A1);
  int tid = threadIdx.x;
  int ks = tid&15, rg = tid>>4;
  int row0 = blk*64 + rg*4;
  float acc[4][16];
  #pragma unroll
  for(int r=0;r<4;r++)
    #pragma unroll
    for(int c=0;c<16;c++) acc[r][c]=0.f;
  const u16* xp = X + (size_t)row0*DIM + ks*128;
  for(int i8=0;i8<16;i8++){
    bf16x8 x0 = *(const bf16x8*)(xp + i8*8);
    bf16x8 x1 = *(const bf16x8*)(xp + DIM + i8*8);
    bf16x8 x2 = *(const bf16x8*)(xp + 2*DIM + i8*8);
    bf16x8 x3 = *(const bf16x8*)(xp + 3*DIM + i8*8);
    #pragma unroll
    for(int e=0;e<8;e++){
      const float4* a = (const float4*)(A + ((size_t)(ks*128 + i8*8 + e))*16);
      float4 a0=a[0], a1=a[1], a2=a[2], a3=a[3];
      float xs0=(float)x0[e], xs1=(float)x1[e], xs2=(float)x2[e], xs3=(float)x3[e];
      #define FMAROW(r, xs) \
        acc[r][0]=fmaf(xs,a0.x,acc[r][0]); acc[r][1]=fmaf(xs,a0.y,acc[r][1]); \
        acc[r][2]=fmaf(xs,a0.z,acc[r][2]); acc[r][3]=fmaf(xs,a0.w,acc[r][3]); \
        acc[r][4]=fmaf(xs,a1.x,acc[r][4]); acc[r][5]=fmaf(xs,a1.y,acc[r][5]); \
        acc[r][6]=fmaf(xs,a1.z,acc[r][6]); acc[r][7]=fmaf(xs,a1.w,acc[r][7]); \
        acc[r][8]=fmaf(xs,a2.x,acc[r][8]); acc[r][9]=fmaf(xs,a2.y,acc[r][9]); \
        acc[r][10]=fmaf(xs,a2.z,acc[r][10]); acc[r][11]=fmaf(xs,a2.w,acc[r][11]); \
        acc[r][12]=fmaf(xs,a3.x,acc[r][12]); acc[r][13]=fmaf(xs,a3.y,acc[r][13]); \
        acc[r][14]=fmaf(xs,a3.z,acc[r][14]); acc[r][15]=fmaf(xs,a3.w,acc[r][15]);
      FMAROW(0, xs0) FMAROW(1, xs1) FMAROW(2, xs2) FMAROW(3, xs3)
      #undef FMAROW
    }
  }
  #pragma unroll
  for(int o=1;o<16;o<<=1){
    #pragma unroll
    for(int r=0;r<4;r++)
      #pragma unroll
      for(int c=0;c<16;c++) acc[r][c] += __shfl_xor(acc[r][c], o);
  }
  if(ks==0){
    #pragma unroll
    for(int r=0;r<4;r++){
      float4* op = (float4*)(out + (size_t)(row0+r)*LDO + mat*16);
      op[0] = make_float4(acc[r][0],acc[r][1],acc[r][2],acc[r][3]);
      op[1] = make_float4(acc[r][4],acc[r][5],acc[r][6],acc[r][7]);
      op[2] = make_float4(acc[r][8],acc[r][9],acc[r][10],acc[r][11]);
      op[3] = make_float4(acc[r][12],acc[r][13],acc[r][14],acc[r][15]);
    }
  }
}

// ---------------- Q path: LoRA-B + LayerNorm + RoPE + scale -> bf16 ----------------
__global__ __launch_bounds__(256) void k_qb(const float* __restrict__ xa,
                                            const float* __restrict__ wqb,
                                            const float* __restrict__ bq,
                                            const float* __restrict__ nqw,
                                            const float* __restrict__ nqb,
                                            const float* __restrict__ cosT,
                                            const float* __restrict__ sinT,
                                            u16* __restrict__ qout){
  __shared__ u16 wl[16*2048];  // 64 KB, bf16 weights
  int tid = threadIdx.x;
  for(int ii=0;ii<32;ii++){
    int f4 = tid + 256*ii;
    float4 v = ((const float4*)wqb)[f4];
    uint2 st; st.x = pack2(v.x,v.y); st.y = pack2(v.z,v.w);
    *(uint2*)&wl[f4*4] = st;
  }
  __syncthreads();
  int j0 = tid*8;
  float bqv[8], nwv[8], nbv[8];
  #pragma unroll
  for(int e=0;e<8;e++){ bqv[e]=bq[j0+e]; nwv[e]=nqw[j0+e]; nbv[e]=nqb[j0+e]; }
  int i0 = (j0&127)>>1;
  for(int rr=0;rr<16;rr++){
    int row = blockIdx.x*16 + rr;
    float xq[16];
    #pragma unroll
    for(int r=0;r<16;r++) xq[r] = xa[(size_t)row*48 + r];
    float pre[8];
    #pragma unroll
    for(int e=0;e<8;e++) pre[e]=0.f;
    #pragma unroll
    for(int r=0;r<16;r++){
      bf16x8 wv = *(const bf16x8*)&wl[r*2048 + j0];
      #pragma unroll
      for(int e=0;e<8;e++) pre[e] = fmaf(xq[r], (float)wv[e], pre[e]);
    }
    #pragma unroll
    for(int e=0;e<8;e++) pre[e] = pre[e]*0.0625f + bqv[e];
    float s=0.f, sq=0.f;
    #pragma unroll
    for(int e=0;e<8;e++){ s+=pre[e]; sq+=pre[e]*pre[e]; }
    float2 red = blockReduceSum2(s, sq);
    float mu = red.x*(1.0f/DIM);
    float var = red.y*(1.0f/DIM) - mu*mu;
    float rstd = rsqrtf(var + EPS);
    float qn[8];
    #pragma unroll
    for(int e=0;e<8;e++) qn[e] = (pre[e]-mu)*rstd*nwv[e] + nbv[e];
    int spos = row & (SS-1);
    const float* cp = cosT + spos*64;
    const float* sp = sinT + spos*64;
    uint4 st;
    u32 pk[4];
    #pragma unroll
    for(int p=0;p<4;p++){
      float c = cp[i0+p], sn = sp[i0+p];
      float x0 = qn[2*p], x1 = qn[2*p+1];
      pk[p] = pack2((x0*c - x1*sn)*QSCALE, (x0*sn + x1*c)*QSCALE);
    }
    st.x=pk[0]; st.y=pk[1]; st.z=pk[2]; st.w=pk[3];
    *(uint4*)&qout[(size_t)row*2048 + j0] = st;
  }
}

// ---------------- K/V path: LoRA-B (+LN+RoPE for K) -> bf16 ----------------
__global__ __launch_bounds__(256) void k_kvb(const float* __restrict__ xa,
                                             const float* __restrict__ wkb,
                                             const float* __restrict__ bk,
                                             const float* __restrict__ nkw,
                                             const float* __restrict__ nkb,
                                             const float* __restrict__ wvb,
                                             const float* __restrict__ bv,
                                             const float* __restrict__ cosT,
                                             const float* __restrict__ sinT,
                                             u16* __restrict__ kout,
                                             u16* __restrict__ vout){
  __shared__ u16 wl[2*16*1024];  // 64 KB: [0,16K)=wk_b, [16K,32K)=wv_b
  int tid = threadIdx.x;
  for(int ii=0;ii<32;ii++){
    int f4 = tid + 256*ii;
    float4 v = (f4 < 4096) ? ((const float4*)wkb)[f4] : ((const float4*)wvb)[f4-4096];
    uint2 st; st.x = pack2(v.x,v.y); st.y = pack2(v.z,v.w);
    *(uint2*)&wl[f4*4] = st;
  }
  __syncthreads();
  int j0 = tid*4;
  float bkv[4], nwv[4], nbv[4], bvv[4];
  #pragma unroll
  for(int e=0;e<4;e++){ bkv[e]=bk[j0+e]; nwv[e]=nkw[j0+e]; nbv[e]=nkb[j0+e]; bvv[e]=bv[j0+e]; }
  int i0 = (j0&127)>>1;
  for(int rr=0;rr<16;rr++){
    int row = blockIdx.x*16 + rr;
    float xk[16], xv[16];
    #pragma unroll
    for(int r=0;r<16;r++){ xk[r]=xa[(size_t)row*48+16+r]; xv[r]=xa[(size_t)row*48+32+r]; }
    float pk_[4], pv_[4];
    #pragma unroll
    for(int e=0;e<4;e++){ pk_[e]=0.f; pv_[e]=0.f; }
    #pragma unroll
    for(int r=0;r<16;r++){
      bf16x4 wk4 = *(const bf16x4*)&wl[r*1024 + j0];
      bf16x4 wv4 = *(const bf16x4*)&wl[16384 + r*1024 + j0];
      #pragma unroll
      for(int e=0;e<4;e++){ pk_[e]=fmaf(xk[r],(float)wk4[e],pk_[e]); pv_[e]=fmaf(xv[r],(float)wv4[e],pv_[e]); }
    }
    #pragma unroll
    for(int e=0;e<4;e++){ pk_[e]=pk_[e]*0.0625f + bkv[e]; pv_[e]=pv_[e]*0.0625f + bvv[e]; }
    float s=0.f, sq=0.f;
    #pragma unroll
    for(int e=0;e<4;e++){ s+=pk_[e]; sq+=pk_[e]*pk_[e]; }
    float2 red = blockReduceSum2(s, sq);
    float mu = red.x*(1.0f/1024.0f);
    float var = red.y*(1.0f/1024.0f) - mu*mu;
    float rstd = rsqrtf(var + EPS);
    float kn[4];
    #pragma unroll
    for(int e=0;e<4;e++) kn[e] = (pk_[e]-mu)*rstd*nwv[e] + nbv[e];
    int spos = row & (SS-1);
    const float* cp = cosT + spos*64;
    const float* sp = sinT + spos*64;
    uint2 stk;
    { float c=cp[i0],   sn=sp[i0];   stk.x = pack2(kn[0]*c - kn[1]*sn, kn[0]*sn + kn[1]*c); }
    { float c=cp[i0+1], sn=sp[i0+1]; stk.y = pack2(kn[2]*c - kn[3]*sn, kn[2]*sn + kn[3]*c); }
    *(uint2*)&kout[(size_t)row*1024 + j0] = stk;
    uint2 stv; stv.x = pack2(pv_[0],pv_[1]); stv.y = pack2(pv_[2],pv_[3]);
    *(uint2*)&vout[(size_t)row*1024 + j0] = stv;
  }
}

// ---------------- Flash attention + residual add -> d_out (f32 h) ----------------
// grid 512 = b(2) x h(16) x qtile(16); block 512 = 8 waves x 16 q-rows each.
// LDS 36.9KB: K-tile unioned with per-wave P (disjoint lifetime); Vt XOR-swizzled.
__global__ __launch_bounds__(512,4) void k_attn(const u16* __restrict__ qb,
                                                const u16* __restrict__ kb,
                                                const u16* __restrict__ vb,
                                                const float* __restrict__ resid,
                                                float* __restrict__ out){
  __shared__ u16 uKP[9216];   // K [64][136] (8704 u16) / P 8x[16][72] (9216 u16)
  __shared__ u16 Vt[9216];    // V^T [128][72], key index XOR-swizzled by ((d>>3)&7)<<3
  int bid = blockIdx.x;
  int qt = bid & 15;
  int h  = (bid>>4) & 15;
  int b  = bid>>8;
  int kvh = h>>1;
  int tid = threadIdx.x;
  int w = tid>>6, lane = tid&63;
  int lg = lane>>4, l16 = lane&15;

  // Q fragments: wave w owns rows qt*128 + w*16 .. +15
  bf16x8 qf[4];
  {
    int s = qt*128 + w*16 + l16;
    const u16* qp = qb + ((size_t)(b*SS + s))*DIM + h*HD + lg*8;
    qf[0] = *(const bf16x8*)(qp);
    qf[1] = *(const bf16x8*)(qp+32);
    qf[2] = *(const bf16x8*)(qp+64);
    qf[3] = *(const bf16x8*)(qp+96);
  }
  f32x4 acc[8];
  #pragma unroll
  for(int n=0;n<8;n++) acc[n] = (f32x4){0.f,0.f,0.f,0.f};
  float mrow[4], lrow[4];
  #pragma unroll
  for(int r=0;r<4;r++){ mrow[r] = -INFINITY; lrow[r] = 0.f; }

  u16* Pw = uKP + w*1152;

  for(int kt=0; kt<SS/64; kt++){
    // stage K [key][d] (linear, pad 136) and V^T [d][key^swz] (pad 72)
    #pragma unroll
    for(int jj=0;jj<2;jj++){
      int mi = tid + 512*jj;
      int key = mi>>4, g = mi&15, d0 = g*8;
      size_t gidx = ((size_t)(b*SS + kt*64 + key)*NKVH + kvh)*HD + d0;
      *(uint4*)&uKP[key*136 + d0] = *(const uint4*)(kb + gidx);
      uint4 vv = *(const uint4*)(vb + gidx);
      int vb0 = d0*72 + (key ^ ((g&7)<<3));
      Vt[vb0      ] = (u16)(vv.x); Vt[vb0 + 72 ] = (u16)(vv.x>>16);
      Vt[vb0 + 144] = (u16)(vv.y); Vt[vb0 + 216] = (u16)(vv.y>>16);
      Vt[vb0 + 288] = (u16)(vv.z); Vt[vb0 + 360] = (u16)(vv.z>>16);
      Vt[vb0 + 432] = (u16)(vv.w); Vt[vb0 + 504] = (u16)(vv.w>>16);
    }
    __syncthreads();                       // B1: staging visible
    // S = Q K^T  (16 MFMA)
    f32x4 sacc[4];
    #pragma unroll
    for(int nb=0;nb<4;nb++){
      f32x4 s = (f32x4){0.f,0.f,0.f,0.f};
      #pragma unroll
      for(int c=0;c<4;c++){
        bf16x8 kf = *(const bf16x8*)&uKP[(nb*16 + l16)*136 + c*32 + lg*8];
        s = __builtin_amdgcn_mfma_f32_16x16x32_bf16(qf[c], kf, s, 0,0,0);
      }
      sacc[nb] = s;
    }
    // online softmax (registers only)
    float alpha[4];
    #pragma unroll
    for(int r=0;r<4;r++){
      float mx = fmaxf(fmaxf(sacc[0][r], sacc[1][r]), fmaxf(sacc[2][r], sacc[3][r]));
      mx = fmaxf(mx, __shfl_xor(mx,1));
      mx = fmaxf(mx, __shfl_xor(mx,2));
      mx = fmaxf(mx, __shfl_xor(mx,4));
      mx = fmaxf(mx, __shfl_xor(mx,8));
      float mnew = fmaxf(mrow[r], mx);
      alpha[r] = __expf(mrow[r] - mnew);
      mrow[r] = mnew;
      float rs = 0.f;
      #pragma unroll
      for(int nb=0;nb<4;nb++){
        float p = __expf(sacc[nb][r] - mnew);
        sacc[nb][r] = p;
        rs += p;
      }
      rs += __shfl_xor(rs,1);
      rs += __shfl_xor(rs,2);
      rs += __shfl_xor(rs,4);
      rs += __shfl_xor(rs,8);
      lrow[r] = lrow[r]*alpha[r] + rs;
    }
    #pragma unroll
    for(int n=0;n<8;n++)
      #pragma unroll
      for(int r=0;r<4;r++) acc[n][r] *= alpha[r];
    __syncthreads();                       // B2: all waves done reading K -> P may overwrite
    #pragma unroll
    for(int nb=0;nb<4;nb++)
      #pragma unroll
      for(int r=0;r<4;r++)
        Pw[(lg*4 + r)*72 + nb*16 + l16] = f2bf(sacc[nb][r]);
    // O += P V  (16 MFMA)
    #pragma unroll
    for(int c2=0;c2<2;c2++){
      bf16x8 pf = *(const bf16x8*)&Pw[l16*72 + c2*32 + lg*8];
      #pragma unroll
      for(int n=0;n<8;n++){
        int drow = n*16 + l16;
        bf16x8 vf = *(const bf16x8*)&Vt[drow*72 + ((c2*32 + lg*8) ^ (((drow>>3)&7)<<3))];
        acc[n] = __builtin_amdgcn_mfma_f32_16x16x32_bf16(pf, vf, acc[n], 0,0,0);
      }
    }
    __syncthreads();                       // B3: P/Vt reads done before next staging
  }
  // epilogue: divide by l, add residual, write h (f32)
  #pragma unroll
  for(int r=0;r<4;r++){
    float inv = 1.0f/lrow[r];
    int s = qt*128 + w*16 + lg*4 + r;
    size_t base = ((size_t)(b*SS + s))*DIM + h*HD;
    #pragma unroll
    for(int n=0;n<8;n++){
      int d = n*16 + l16;
      out[base + d] = resid[base + d] + acc[n][r]*inv;
    }
  }
}

// ---------------- fused FFN: racc[row][16] = silu/gate path @ w2_a ----------------
// 4 rows/block, acc[64] per thread (fits registers, no scratch spill).
__global__ __launch_bounds__(256) void k_ffn(const float* __restrict__ t13,
                                             const float* __restrict__ w1b,
                                             const float* __restrict__ b1,
                                             const float* __restrict__ w3b,
                                             const float* __restrict__ b3,
                                             const float* __restrict__ w2a,
                                             float* __restrict__ racc){
  __shared__ float tl[4][32];
  __shared__ float red[4][64];
  int tid = threadIdx.x;
  int row0 = blockIdx.x*4;
  if(tid<128) tl[tid>>5][tid&31] = t13[(size_t)row0*32 + tid];
  __syncthreads();
  float acc[64];
  #pragma unroll
  for(int v=0;v<64;v++) acc[v]=0.f;
  for(int ii=0;ii<INNER/256;ii++){
    int j = tid + 256*ii;
    float w1c[16], w3c[16], w2r[16];
    #pragma unroll
    for(int r=0;r<16;r++){ w1c[r]=w1b[(size_t)r*INNER+j]; w3c[r]=w3b[(size_t)r*INNER+j]; }
    {
      const float4* wp = (const float4*)(w2a + (size_t)j*16);
      #pragma unroll
      for(int q=0;q<4;q++){ float4 t=wp[q]; w2r[q*4]=t.x; w2r[q*4+1]=t.y; w2r[q*4+2]=t.z; w2r[q*4+3]=t.w; }
    }
    float bb1 = b1[j], bb3 = b3[j];
    #pragma unroll
    for(int rr=0;rr<4;rr++){
      float a1=0.f, a3=0.f;
      #pragma unroll
      for(int r=0;r<16;r++){ a1 = fmaf(tl[rr][r], w1c[r], a1); a3 = fmaf(tl[rr][16+r], w3c[r], a3); }
      a1 = a1*0.0625f + bb1;
      a3 = a3*0.0625f + bb3;
      float u = (a1/(1.0f+__expf(-a1))) * a3;
      #pragma unroll
      for(int c=0;c<16;c++) acc[rr*16+c] = fmaf(u, w2r[c], acc[rr*16+c]);
    }
  }
  #pragma unroll
  for(int o=1;o<64;o<<=1){
    #pragma unroll
    for(int v=0;v<64;v++) acc[v] += __shfl_xor(acc[v], o);
  }
  int wv = tid>>6, lane = tid&63;
  if(lane==0){
    #pragma unroll
    for(int v=0;v<64;v++) red[wv][v] = acc[v];
  }
  __syncthreads();
  if(tid<64){
    float sum = red[0][tid]+red[1][tid]+red[2][tid]+red[3][tid];
    racc[(size_t)(row0 + (tid>>4))*16 + (tid&15)] = sum;
  }
}

// ---------------- final: out = h + racc @ w2_b /16 + b2 ----------------
__global__ __launch_bounds__(256) void k_out(const float* __restrict__ racc,
                                             const float* __restrict__ w2b,
                                             const float* __restrict__ b2,
                                             float* __restrict__ io){
  __shared__ u16 wl[16*2048];
  int tid = threadIdx.x;
  for(int ii=0;ii<32;ii++){
    int f4 = tid + 256*ii;
    float4 v = ((const float4*)w2b)[f4];
    uint2 st; st.x = pack2(v.x,v.y); st.y = pack2(v.z,v.w);
    *(uint2*)&wl[f4*4] = st;
  }
  __syncthreads();
  int j0 = tid*8;
  float b2v[8];
  #pragma unroll
  for(int e=0;e<8;e++) b2v[e] = b2[j0+e];
  for(int rr=0;rr<16;rr++){
    int row = blockIdx.x*16 + rr;
    float rc[16];
    #pragma unroll
    for(int r=0;r<16;r++) rc[r] = racc[(size_t)row*16 + r];
    float pre[8];
    #pragma unroll
    for(int e=0;e<8;e++) pre[e]=0.f;
    #pragma unroll
    for(int r=0;r<16;r++){
      bf16x8 wv = *(const bf16x8*)&wl[r*2048 + j0];
      #pragma unroll
      for(int e=0;e<8;e++) pre[e] = fmaf(rc[r], (float)wv[e], pre[e]);
    }
    float* op = io + (size_t)row*DIM + j0;
    float4 h0 = ((const float4*)op)[0];
    float4 h1 = ((const float4*)op)[1];
    float4 o0, o1;
    o0.x = h0.x + pre[0]*0.0625f + b2v[0];
    o0.y = h0.y + pre[1]*0.0625f + b2v[1];
    o0.z = h0.z + pre[2]*0.0625f + b2v[2];
    o0.w = h0.w + pre[3]*0.0625f + b2v[3];
    o1.x = h1.x + pre[4]*0.0625f + b2v[4];
    o1.y = h1.y + pre[5]*0.0625f + b2v[5];
    o1.z = h1.z + pre[6]*0.0625f + b2v[6];
    o1.w = h1.w + pre[7]*0.0625f + b2v[7];
    ((float4*)op)[0] = o0;
    ((float4*)op)[1] = o1;
  }
}

extern "C" void kernel_launch(void* const* d_in, const int* in_sizes, int n_in,
                              void* d_out, int out_size, void* d_ws, size_t ws_size,
                              hipStream_t stream){
  const float* hidden = (const float*)d_in[0];
  // d_in[1] attention_mask: all-true, no-op in reference -> ignored
  const float* cosT = (const float*)d_in[2];
  const float* sinT = (const float*)d_in[3];
  const float* wq_a = (const float*)d_in[4];
  const float* wq_b = (const float*)d_in[5];
  const float* bq   = (const float*)d_in[6];
  const float* wk_a = (const float*)d_in[7];
  const float* wk_b = (const float*)d_in[8];
  const float* bk   = (const float*)d_in[9];
  const float* wv_a = (const float*)d_in[10];
  const float* wv_b = (const float*)d_in[11];
  const float* bv   = (const float*)d_in[12];
  const float* nqw  = (const float*)d_in[13];
  const float* nqb  = (const float*)d_in[14];
  const float* nkw  = (const float*)d_in[15];
  const float* nkb  = (const float*)d_in[16];
  const float* w1a  = (const float*)d_in[17];
  const float* w1b  = (const float*)d_in[18];
  const float* b1   = (const float*)d_in[19];
  const float* w3a  = (const float*)d_in[20];
  const float* w3b  = (const float*)d_in[21];
  const float* b3   = (const float*)d_in[22];
  const float* w2a  = (const float*)d_in[23];
  const float* w2b  = (const float*)d_in[24];
  const float* b2   = (const float*)d_in[25];
  const float* normw  = (const float*)d_in[26];
  const float* fnormw = (const float*)d_in[27];
  float* out = (float*)d_out;

  // ws layout (~35.1 MB)
  char* p = (char*)d_ws;
  u16* bufA = (u16*)p; p += (size_t)NROWS*DIM*2;       // nh, then nf
  u16* qbuf = (u16*)p; p += (size_t)NROWS*DIM*2;       // q bf16
  u16* kbuf = (u16*)p; p += (size_t)NROWS*1024*2;
  u16* vbuf = (u16*)p; p += (size_t)NROWS*1024*2;
  float* xa   = (float*)p; p += (size_t)NROWS*48*4;
  float* t13  = (float*)p; p += (size_t)NROWS*32*4;
  float* racc = (float*)p; p += (size_t)NROWS*16*4;

  k_rms<<<NROWS,256,0,stream>>>(hidden, normw, bufA);                       // nh
  k_loraAm<3><<<192,256,0,stream>>>(bufA, wq_a, wk_a, wv_a, xa);
  k_qb <<<NROWS/16,256,0,stream>>>(xa, wq_b, bq, nqw, nqb, cosT, sinT, qbuf);
  k_kvb<<<NROWS/16,256,0,stream>>>(xa, wk_b, bk, nkw, nkb, wv_b, bv, cosT, sinT, kbuf, vbuf);
  k_attn<<<512,512,0,stream>>>(qbuf, kbuf, vbuf, hidden, out);              // out = h
  k_rms<<<NROWS,256,0,stream>>>(out, fnormw, bufA);                         // nf
  k_loraAm<2><<<128,256,0,stream>>>(bufA, w1a, w3a, nullptr, t13);
  k_ffn<<<NROWS/4,256,0,stream>>>(t13, w1b, b1, w3b, b3, w2a, racc);
  k_out<<<NROWS/16,256,0,stream>>>(racc, w2b, b2, out);
}

// Round 4
// 470.443 us; speedup vs baseline: 2.6789x; 1.1623x over previous
//
#include <hip/hip_runtime.h>
#include <math.h>

typedef unsigned short u16;
typedef unsigned int u32;
typedef __bf16 bf16x8 __attribute__((ext_vector_type(8)));
typedef __bf16 bf16x4 __attribute__((ext_vector_type(4)));
typedef float f32x4 __attribute__((ext_vector_type(4)));

#define DIM 2048
#define NHEADS 16
#define NKVH 8
#define HD 128
#define RANK 16
#define INNER 5632
#define BB 2
#define SS 2048
#define NROWS (BB*SS)
#define EPS 1e-5f
#define QSC2 0.12751743560829201f   /* log2(e)/sqrt(128): exp2-domain softmax */
#define LOG2E 1.4426950408889634f

__device__ inline float bf2f(u16 u){ u32 x = ((u32)u)<<16; float f; __builtin_memcpy(&f,&x,4); return f; }
__device__ inline u16 f2bf(float f){ u32 u; __builtin_memcpy(&u,&f,4); u32 r = u + 0x7fffu + ((u>>16)&1u); return (u16)(r>>16); }
__device__ inline u32 pack2(float a, float b){ return (u32)f2bf(a) | ((u32)f2bf(b)<<16); }

__device__ inline float blockReduceSum(float v){
  __shared__ float r[4];
  #pragma unroll
  for(int o=1;o<64;o<<=1) v += __shfl_xor(v, o);
  int wv = threadIdx.x>>6;
  __syncthreads();
  if((threadIdx.x&63)==0) r[wv] = v;
  __syncthreads();
  return r[0]+r[1]+r[2]+r[3];
}

__device__ inline f32x4 blockReduceSum4(f32x4 v){
  __shared__ f32x4 r4[4];
  #pragma unroll
  for(int o=1;o<64;o<<=1){
    v.x += __shfl_xor(v.x,o); v.y += __shfl_xor(v.y,o);
    v.z += __shfl_xor(v.z,o); v.w += __shfl_xor(v.w,o);
  }
  int wv = threadIdx.x>>6;
  __syncthreads();
  if((threadIdx.x&63)==0) r4[wv]=v;
  __syncthreads();
  return r4[0]+r4[1]+r4[2]+r4[3];
}

// ---------------- RMSNorm: f32 in -> bf16 out (row = block) ----------------
__global__ __launch_bounds__(256) void k_rms(const float* __restrict__ x,
                                             const float* __restrict__ w,
                                             u16* __restrict__ out){
  size_t base = (size_t)blockIdx.x*DIM;
  int tid = threadIdx.x;
  float4 v0 = ((const float4*)(x+base))[tid*2];
  float4 v1 = ((const float4*)(x+base))[tid*2+1];
  float ss = v0.x*v0.x+v0.y*v0.y+v0.z*v0.z+v0.w*v0.w
           + v1.x*v1.x+v1.y*v1.y+v1.z*v1.z+v1.w*v1.w;
  ss = blockReduceSum(ss);
  float rstd = rsqrtf(ss*(1.0f/DIM) + EPS);
  float4 w0 = ((const float4*)w)[tid*2];
  float4 w1 = ((const float4*)w)[tid*2+1];
  uint4 st;
  st.x = pack2(v0.x*w0.x*rstd, v0.y*w0.y*rstd);
  st.y = pack2(v0.z*w0.z*rstd, v0.w*w0.w*rstd);
  st.z = pack2(v1.x*w1.x*rstd, v1.y*w1.y*rstd);
  st.w = pack2(v1.z*w1.z*rstd, v1.w*w1.w*rstd);
  *(uint4*)&out[base + tid*8] = st;
}

// ---------------- LoRA-A: 4 rows/thread amortizes A loads; NMAT matrices per launch ----
template<int NMAT>
__global__ __launch_bounds__(256) void k_loraAm(const u16* __restrict__ X,
                                                const float* __restrict__ A0,
                                                const float* __restrict__ A1,
                                                const float* __restrict__ A2,
                                                float* __restrict__ out){
  constexpr int LDO = NMAT*16;
  int mat = blockIdx.x >> 6;
  int blk = blockIdx.x & 63;
  const float* A = (mat==0) ? A0 : ((NMAT>2 && mat==2) ? A2 : A1);
  int tid = threadIdx.x;
  int ks = tid&15, rg = tid>>4;
  int row0 = blk*64 + rg*4;
  float acc[4][16];
  #pragma unroll
  for(int r=0;r<4;r++)
    #pragma unroll
    for(int c=0;c<16;c++) acc[r][c]=0.f;
  const u16* xp = X + (size_t)row0*DIM + ks*128;
  for(int i8=0;i8<16;i8++){
    bf16x8 x0 = *(const bf16x8*)(xp + i8*8);
    bf16x8 x1 = *(const bf16x8*)(xp + DIM + i8*8);
    bf16x8 x2 = *(const bf16x8*)(xp + 2*DIM + i8*8);
    bf16x8 x3 = *(const bf16x8*)(xp + 3*DIM + i8*8);
    #pragma unroll
    for(int e=0;e<8;e++){
      const float4* a = (const float4*)(A + ((size_t)(ks*128 + i8*8 + e))*16);
      float4 a0=a[0], a1=a[1], a2=a[2], a3=a[3];
      float xs0=(float)x0[e], xs1=(float)x1[e], xs2=(float)x2[e], xs3=(float)x3[e];
      #define FMAROW(r, xs) \
        acc[r][0]=fmaf(xs,a0.x,acc[r][0]); acc[r][1]=fmaf(xs,a0.y,acc[r][1]); \
        acc[r][2]=fmaf(xs,a0.z,acc[r][2]); acc[r][3]=fmaf(xs,a0.w,acc[r][3]); \
        acc[r][4]=fmaf(xs,a1.x,acc[r][4]); acc[r][5]=fmaf(xs,a1.y,acc[r][5]); \
        acc[r][6]=fmaf(xs,a1.z,acc[r][6]); acc[r][7]=fmaf(xs,a1.w,acc[r][7]); \
        acc[r][8]=fmaf(xs,a2.x,acc[r][8]); acc[r][9]=fmaf(xs,a2.y,acc[r][9]); \
        acc[r][10]=fmaf(xs,a2.z,acc[r][10]); acc[r][11]=fmaf(xs,a2.w,acc[r][11]); \
        acc[r][12]=fmaf(xs,a3.x,acc[r][12]); acc[r][13]=fmaf(xs,a3.y,acc[r][13]); \
        acc[r][14]=fmaf(xs,a3.z,acc[r][14]); acc[r][15]=fmaf(xs,a3.w,acc[r][15]);
      FMAROW(0, xs0) FMAROW(1, xs1) FMAROW(2, xs2) FMAROW(3, xs3)
      #undef FMAROW
    }
  }
  #pragma unroll
  for(int o=1;o<16;o<<=1){
    #pragma unroll
    for(int r=0;r<4;r++)
      #pragma unroll
      for(int c=0;c<16;c++) acc[r][c] += __shfl_xor(acc[r][c], o);
  }
  if(ks==0){
    #pragma unroll
    for(int r=0;r<4;r++){
      float4* op = (float4*)(out + (size_t)(row0+r)*LDO + mat*16);
      op[0] = make_float4(acc[r][0],acc[r][1],acc[r][2],acc[r][3]);
      op[1] = make_float4(acc[r][4],acc[r][5],acc[r][6],acc[r][7]);
      op[2] = make_float4(acc[r][8],acc[r][9],acc[r][10],acc[r][11]);
      op[3] = make_float4(acc[r][12],acc[r][13],acc[r][14],acc[r][15]);
    }
  }
}

// ---------------- Q path: LoRA-B + LayerNorm + RoPE + scale -> bf16 ----------------
__global__ __launch_bounds__(256) void k_qb(const float* __restrict__ xa,
                                            const float* __restrict__ wqb,
                                            const float* __restrict__ bq,
                                            const float* __restrict__ nqw,
                                            const float* __restrict__ nqb,
                                            const float* __restrict__ cosT,
                                            const float* __restrict__ sinT,
                                            u16* __restrict__ qout){
  __shared__ u16 wl[16*2048];  // 64 KB, bf16 weights
  int tid = threadIdx.x;
  for(int ii=0;ii<32;ii++){
    int f4 = tid + 256*ii;
    float4 v = ((const float4*)wqb)[f4];
    uint2 st; st.x = pack2(v.x,v.y); st.y = pack2(v.z,v.w);
    *(uint2*)&wl[f4*4] = st;
  }
  __syncthreads();
  int j0 = tid*8;
  float bqv[8], nwv[8], nbv[8];
  #pragma unroll
  for(int e=0;e<8;e++){ bqv[e]=bq[j0+e]; nwv[e]=nqw[j0+e]; nbv[e]=nqb[j0+e]; }
  int i0 = (j0&127)>>1;
  for(int rp=0;rp<8;rp++){
    int row = blockIdx.x*16 + rp*2;
    float pre[2][8];
    #pragma unroll
    for(int rr=0;rr<2;rr++){
      float xq[16];
      #pragma unroll
      for(int r=0;r<16;r++) xq[r] = xa[(size_t)(row+rr)*48 + r];
      #pragma unroll
      for(int e=0;e<8;e++) pre[rr][e]=0.f;
      #pragma unroll
      for(int r=0;r<16;r++){
        bf16x8 wv = *(const bf16x8*)&wl[r*2048 + j0];
        #pragma unroll
        for(int e=0;e<8;e++) pre[rr][e] = fmaf(xq[r], (float)wv[e], pre[rr][e]);
      }
      #pragma unroll
      for(int e=0;e<8;e++) pre[rr][e] = pre[rr][e]*0.0625f + bqv[e];
    }
    f32x4 sv = (f32x4){0.f,0.f,0.f,0.f};
    #pragma unroll
    for(int e=0;e<8;e++){
      sv.x += pre[0][e]; sv.y += pre[0][e]*pre[0][e];
      sv.z += pre[1][e]; sv.w += pre[1][e]*pre[1][e];
    }
    f32x4 red = blockReduceSum4(sv);
    #pragma unroll
    for(int rr=0;rr<2;rr++){
      float mu  = (rr?red.z:red.x)*(1.0f/DIM);
      float var = (rr?red.w:red.y)*(1.0f/DIM) - mu*mu;
      float rstd = rsqrtf(var + EPS);
      float qn[8];
      #pragma unroll
      for(int e=0;e<8;e++) qn[e] = (pre[rr][e]-mu)*rstd*nwv[e] + nbv[e];
      int spos = (row+rr) & (SS-1);
      const float* cp = cosT + spos*64;
      const float* sp = sinT + spos*64;
      uint4 st;
      u32 pk[4];
      #pragma unroll
      for(int p=0;p<4;p++){
        float c = cp[i0+p], sn = sp[i0+p];
        float x0 = qn[2*p], x1 = qn[2*p+1];
        pk[p] = pack2((x0*c - x1*sn)*QSC2, (x0*sn + x1*c)*QSC2);
      }
      st.x=pk[0]; st.y=pk[1]; st.z=pk[2]; st.w=pk[3];
      *(uint4*)&qout[(size_t)(row+rr)*2048 + j0] = st;
    }
  }
}

// ---------------- K/V path: LoRA-B (+LN+RoPE for K) -> bf16 ----------------
__global__ __launch_bounds__(256) void k_kvb(const float* __restrict__ xa,
                                             const float* __restrict__ wkb,
                                             const float* __restrict__ bk,
                                             const float* __restrict__ nkw,
                                             const float* __restrict__ nkb,
                                             const float* __restrict__ wvb,
                                             const float* __restrict__ bv,
                                             const float* __restrict__ cosT,
                                             const float* __restrict__ sinT,
                                             u16* __restrict__ kout,
                                             u16* __restrict__ vout){
  __shared__ u16 wl[2*16*1024];  // 64 KB: [0,16K)=wk_b, [16K,32K)=wv_b
  int tid = threadIdx.x;
  for(int ii=0;ii<32;ii++){
    int f4 = tid + 256*ii;
    float4 v = (f4 < 4096) ? ((const float4*)wkb)[f4] : ((const float4*)wvb)[f4-4096];
    uint2 st; st.x = pack2(v.x,v.y); st.y = pack2(v.z,v.w);
    *(uint2*)&wl[f4*4] = st;
  }
  __syncthreads();
  int j0 = tid*4;
  float bkv[4], nwv[4], nbv[4], bvv[4];
  #pragma unroll
  for(int e=0;e<4;e++){ bkv[e]=bk[j0+e]; nwv[e]=nkw[j0+e]; nbv[e]=nkb[j0+e]; bvv[e]=bv[j0+e]; }
  int i0 = (j0&127)>>1;
  for(int rp=0;rp<8;rp++){
    int row = blockIdx.x*16 + rp*2;
    float pk_[2][4], pv_[2][4];
    #pragma unroll
    for(int rr=0;rr<2;rr++){
      float xk[16], xv[16];
      #pragma unroll
      for(int r=0;r<16;r++){ xk[r]=xa[(size_t)(row+rr)*48+16+r]; xv[r]=xa[(size_t)(row+rr)*48+32+r]; }
      #pragma unroll
      for(int e=0;e<4;e++){ pk_[rr][e]=0.f; pv_[rr][e]=0.f; }
      #pragma unroll
      for(int r=0;r<16;r++){
        bf16x4 wk4 = *(const bf16x4*)&wl[r*1024 + j0];
        bf16x4 wv4 = *(const bf16x4*)&wl[16384 + r*1024 + j0];
        #pragma unroll
        for(int e=0;e<4;e++){ pk_[rr][e]=fmaf(xk[r],(float)wk4[e],pk_[rr][e]); pv_[rr][e]=fmaf(xv[r],(float)wv4[e],pv_[rr][e]); }
      }
      #pragma unroll
      for(int e=0;e<4;e++){ pk_[rr][e]=pk_[rr][e]*0.0625f + bkv[e]; pv_[rr][e]=pv_[rr][e]*0.0625f + bvv[e]; }
    }
    f32x4 sv = (f32x4){0.f,0.f,0.f,0.f};
    #pragma unroll
    for(int e=0;e<4;e++){
      sv.x += pk_[0][e]; sv.y += pk_[0][e]*pk_[0][e];
      sv.z += pk_[1][e]; sv.w += pk_[1][e]*pk_[1][e];
    }
    f32x4 red = blockReduceSum4(sv);
    #pragma unroll
    for(int rr=0;rr<2;rr++){
      float mu  = (rr?red.z:red.x)*(1.0f/1024.0f);
      float var = (rr?red.w:red.y)*(1.0f/1024.0f) - mu*mu;
      float rstd = rsqrtf(var + EPS);
      float kn[4];
      #pragma unroll
      for(int e=0;e<4;e++) kn[e] = (pk_[rr][e]-mu)*rstd*nwv[e] + nbv[e];
      int spos = (row+rr) & (SS-1);
      const float* cp = cosT + spos*64;
      const float* sp = sinT + spos*64;
      uint2 stk;
      { float c=cp[i0],   sn=sp[i0];   stk.x = pack2(kn[0]*c - kn[1]*sn, kn[0]*sn + kn[1]*c); }
      { float c=cp[i0+1], sn=sp[i0+1]; stk.y = pack2(kn[2]*c - kn[3]*sn, kn[2]*sn + kn[3]*c); }
      *(uint2*)&kout[(size_t)(row+rr)*1024 + j0] = stk;
      uint2 stv; stv.x = pack2(pv_[rr][0],pv_[rr][1]); stv.y = pack2(pv_[rr][2],pv_[rr][3]);
      *(uint2*)&vout[(size_t)(row+rr)*1024 + j0] = stv;
    }
  }
}

// ---------------- Flash attention + residual add -> d_out (f32 h) ----------------
// grid 512 = b(2) x h(16) x qtile(16); block 512 = 8 waves x 16 q-rows each.
// Reg-staged double buffer: load kt+1 to VGPRs early, LDS-write after barrier.
// LDS 54.3KB (2 blocks/CU): K[64][136] + Vt[128][72] swizzled + per-wave P.
__global__ __launch_bounds__(512,4) void k_attn(const u16* __restrict__ qb,
                                                const u16* __restrict__ kb,
                                                const u16* __restrict__ vb,
                                                const float* __restrict__ resid,
                                                float* __restrict__ out){
  __shared__ u16 Kl[64*136];
  __shared__ u16 Vt[128*72];
  __shared__ u16 Pl[8][16*72];
  int bid = blockIdx.x;
  int qt = bid & 15;
  int h  = (bid>>4) & 15;
  int b  = bid>>8;
  int kvh = h>>1;
  int tid = threadIdx.x;
  int w = tid>>6, lane = tid&63;
  int lg = lane>>4, l16 = lane&15;

  bf16x8 qf[4];
  {
    int s = qt*128 + w*16 + l16;
    const u16* qp = qb + ((size_t)(b*SS + s))*DIM + h*HD + lg*8;
    qf[0] = *(const bf16x8*)(qp);
    qf[1] = *(const bf16x8*)(qp+32);
    qf[2] = *(const bf16x8*)(qp+64);
    qf[3] = *(const bf16x8*)(qp+96);
  }
  f32x4 acc[8];
  #pragma unroll
  for(int n=0;n<8;n++) acc[n] = (f32x4){0.f,0.f,0.f,0.f};
  float mrow[4], lrow[4];
  #pragma unroll
  for(int r=0;r<4;r++){ mrow[r] = -INFINITY; lrow[r] = 0.f; }

  u16* Pw = Pl[w];
  int skey = tid>>4, sg = tid&15, sd0 = (tid&15)*8;
  int skey2 = (tid+512)>>4, sd02 = sd0;  // jj=1: same g, key+32
  uint4 kst[2], vst[2];

  auto load_stage = [&](int kt){
    size_t g0 = ((size_t)(b*SS + kt*64 + skey)*NKVH + kvh)*HD + sd0;
    size_t g1 = ((size_t)(b*SS + kt*64 + skey2)*NKVH + kvh)*HD + sd02;
    kst[0] = *(const uint4*)(kb+g0); vst[0] = *(const uint4*)(vb+g0);
    kst[1] = *(const uint4*)(kb+g1); vst[1] = *(const uint4*)(vb+g1);
  };
  auto store_stage = [&](){
    #pragma unroll
    for(int jj=0;jj<2;jj++){
      int key = jj ? skey2 : skey;
      *(uint4*)&Kl[key*136 + sd0] = kst[jj];
      uint4 vv = vst[jj];
      int vb0 = sd0*72 + (key ^ ((sg&7)<<3));
      Vt[vb0      ] = (u16)(vv.x); Vt[vb0 + 72 ] = (u16)(vv.x>>16);
      Vt[vb0 + 144] = (u16)(vv.y); Vt[vb0 + 216] = (u16)(vv.y>>16);
      Vt[vb0 + 288] = (u16)(vv.z); Vt[vb0 + 360] = (u16)(vv.z>>16);
      Vt[vb0 + 432] = (u16)(vv.w); Vt[vb0 + 504] = (u16)(vv.w>>16);
    }
  };

  load_stage(0);
  store_stage();
  __syncthreads();

  for(int kt=0; kt<SS/64; kt++){
    bool more = (kt+1) < SS/64;
    if(more) load_stage(kt+1);          // in-flight during compute
    // S = Q K^T  (16 MFMA)
    f32x4 sacc[4];
    #pragma unroll
    for(int nb=0;nb<4;nb++){
      f32x4 s = (f32x4){0.f,0.f,0.f,0.f};
      #pragma unroll
      for(int c=0;c<4;c++){
        bf16x8 kf = *(const bf16x8*)&Kl[(nb*16 + l16)*136 + c*32 + lg*8];
        s = __builtin_amdgcn_mfma_f32_16x16x32_bf16(qf[c], kf, s, 0,0,0);
      }
      sacc[nb] = s;
    }
    // online softmax in exp2 domain
    float alpha[4];
    #pragma unroll
    for(int r=0;r<4;r++){
      float mx = fmaxf(fmaxf(sacc[0][r], sacc[1][r]), fmaxf(sacc[2][r], sacc[3][r]));
      mx = fmaxf(mx, __shfl_xor(mx,1));
      mx = fmaxf(mx, __shfl_xor(mx,2));
      mx = fmaxf(mx, __shfl_xor(mx,4));
      mx = fmaxf(mx, __shfl_xor(mx,8));
      float mnew = fmaxf(mrow[r], mx);
      alpha[r] = exp2f(mrow[r] - mnew);
      mrow[r] = mnew;
      float rs = 0.f;
      #pragma unroll
      for(int nb=0;nb<4;nb++){
        float p = exp2f(sacc[nb][r] - mnew);
        sacc[nb][r] = p;
        rs += p;
      }
      rs += __shfl_xor(rs,1);
      rs += __shfl_xor(rs,2);
      rs += __shfl_xor(rs,4);
      rs += __shfl_xor(rs,8);
      lrow[r] = lrow[r]*alpha[r] + rs;
    }
    #pragma unroll
    for(int n=0;n<8;n++)
      #pragma unroll
      for(int r=0;r<4;r++) acc[n][r] *= alpha[r];
    // P -> per-wave LDS (wave-private: no barrier needed)
    #pragma unroll
    for(int nb=0;nb<4;nb++)
      #pragma unroll
      for(int r=0;r<4;r++)
        Pw[(lg*4 + r)*72 + nb*16 + l16] = f2bf(sacc[nb][r]);
    // O += P V  (16 MFMA)
    #pragma unroll
    for(int c2=0;c2<2;c2++){
      bf16x8 pf = *(const bf16x8*)&Pw[l16*72 + c2*32 + lg*8];
      #pragma unroll
      for(int n=0;n<8;n++){
        int drow = n*16 + l16;
        bf16x8 vf = *(const bf16x8*)&Vt[drow*72 + ((c2*32 + lg*8) ^ (((drow>>3)&7)<<3))];
        acc[n] = __builtin_amdgcn_mfma_f32_16x16x32_bf16(pf, vf, acc[n], 0,0,0);
      }
    }
    __syncthreads();                     // all waves done reading Kl/Vt
    if(more) store_stage();              // waits vmcnt internally (compiler)
    __syncthreads();                     // staging visible
  }
  // epilogue: divide by l, add residual, write h (f32)
  #pragma unroll
  for(int r=0;r<4;r++){
    float inv = __builtin_amdgcn_rcpf(lrow[r]);
    int s = qt*128 + w*16 + lg*4 + r;
    size_t base = ((size_t)(b*SS + s))*DIM + h*HD;
    #pragma unroll
    for(int n=0;n<8;n++){
      int d = n*16 + l16;
      out[base + d] = resid[base + d] + acc[n][r]*inv;
    }
  }
}

// ---------------- pack FFN weights to bf16 [j][48] = w1|w3|w2a rows ----------------
__global__ __launch_bounds__(256) void k_pack(const float* __restrict__ w1b,
                                              const float* __restrict__ w3b,
                                              const float* __restrict__ w2a,
                                              u16* __restrict__ wpk){
  int j = blockIdx.x*256 + threadIdx.x;
  u32 pw[24];
  #pragma unroll
  for(int i=0;i<8;i++) pw[i]    = pack2(w1b[(size_t)(2*i)*INNER+j], w1b[(size_t)(2*i+1)*INNER+j]);
  #pragma unroll
  for(int i=0;i<8;i++) pw[8+i]  = pack2(w3b[(size_t)(2*i)*INNER+j], w3b[(size_t)(2*i+1)*INNER+j]);
  const float4* wp = (const float4*)(w2a + (size_t)j*16);
  #pragma unroll
  for(int q=0;q<4;q++){ float4 t=wp[q];
    pw[16+2*q] = pack2(t.x,t.y); pw[17+2*q] = pack2(t.z,t.w); }
  uint4* dst = (uint4*)(wpk + (size_t)j*48);
  #pragma unroll
  for(int i=0;i<6;i++) dst[i] = make_uint4(pw[4*i],pw[4*i+1],pw[4*i+2],pw[4*i+3]);
}

// ---------------- fused FFN: racc[row][16], packed bf16 weights ----------------
__global__ __launch_bounds__(256,1) void k_ffn(const float* __restrict__ t13,
                                               const u16* __restrict__ wpk,
                                               const float* __restrict__ b1,
                                               const float* __restrict__ b3,
                                               float* __restrict__ racc){
  __shared__ float tl[4][32];
  __shared__ float red[4][64];
  int tid = threadIdx.x;
  int row0 = blockIdx.x*4;
  if(tid<128) tl[tid>>5][tid&31] = t13[(size_t)row0*32 + tid];
  __syncthreads();
  float acc[64];
  #pragma unroll
  for(int v=0;v<64;v++) acc[v]=0.f;
  for(int ii=0;ii<INNER/256;ii++){
    int j = tid + 256*ii;
    const u16* wr = wpk + (size_t)j*48;
    bf16x8 W1a = *(const bf16x8*)(wr),    W1b = *(const bf16x8*)(wr+8);
    bf16x8 W3a = *(const bf16x8*)(wr+16), W3b = *(const bf16x8*)(wr+24);
    bf16x8 W2a = *(const bf16x8*)(wr+32), W2b = *(const bf16x8*)(wr+40);
    float bb1 = b1[j], bb3 = b3[j];
    #pragma unroll
    for(int rr=0;rr<4;rr++){
      float a1=0.f, a3=0.f;
      #pragma unroll
      for(int r=0;r<8;r++){
        a1 = fmaf(tl[rr][r],    (float)W1a[r], a1);
        a1 = fmaf(tl[rr][8+r],  (float)W1b[r], a1);
        a3 = fmaf(tl[rr][16+r], (float)W3a[r], a3);
        a3 = fmaf(tl[rr][24+r], (float)W3b[r], a3);
      }
      a1 = a1*0.0625f + bb1;
      a3 = a3*0.0625f + bb3;
      float u = a1*__builtin_amdgcn_rcpf(1.0f+exp2f(-a1*LOG2E)) * a3;
      #pragma unroll
      for(int c=0;c<8;c++){
        acc[rr*16+c]   = fmaf(u, (float)W2a[c], acc[rr*16+c]);
        acc[rr*16+8+c] = fmaf(u, (float)W2b[c], acc[rr*16+8+c]);
      }
    }
  }
  #pragma unroll
  for(int o=1;o<64;o<<=1){
    #pragma unroll
    for(int v=0;v<64;v++) acc[v] += __shfl_xor(acc[v], o);
  }
  int wv = tid>>6, lane = tid&63;
  if(lane==0){
    #pragma unroll
    for(int v=0;v<64;v++) red[wv][v] = acc[v];
  }
  __syncthreads();
  if(tid<64){
    float sum = red[0][tid]+red[1][tid]+red[2][tid]+red[3][tid];
    racc[(size_t)(row0 + (tid>>4))*16 + (tid&15)] = sum;
  }
}

// ---------------- final: out = h + racc @ w2_b /16 + b2 ----------------
__global__ __launch_bounds__(256) void k_out(const float* __restrict__ racc,
                                             const float* __restrict__ w2b,
                                             const float* __restrict__ b2,
                                             float* __restrict__ io){
  __shared__ u16 wl[16*2048];
  int tid = threadIdx.x;
  for(int ii=0;ii<32;ii++){
    int f4 = tid + 256*ii;
    float4 v = ((const float4*)w2b)[f4];
    uint2 st; st.x = pack2(v.x,v.y); st.y = pack2(v.z,v.w);
    *(uint2*)&wl[f4*4] = st;
  }
  __syncthreads();
  int j0 = tid*8;
  float b2v[8];
  #pragma unroll
  for(int e=0;e<8;e++) b2v[e] = b2[j0+e];
  for(int rr=0;rr<16;rr++){
    int row = blockIdx.x*16 + rr;
    float rc[16];
    #pragma unroll
    for(int r=0;r<16;r++) rc[r] = racc[(size_t)row*16 + r];
    float pre[8];
    #pragma unroll
    for(int e=0;e<8;e++) pre[e]=0.f;
    #pragma unroll
    for(int r=0;r<16;r++){
      bf16x8 wv = *(const bf16x8*)&wl[r*2048 + j0];
      #pragma unroll
      for(int e=0;e<8;e++) pre[e] = fmaf(rc[r], (float)wv[e], pre[e]);
    }
    float* op = io + (size_t)row*DIM + j0;
    float4 h0 = ((const float4*)op)[0];
    float4 h1 = ((const float4*)op)[1];
    float4 o0, o1;
    o0.x = h0.x + pre[0]*0.0625f + b2v[0];
    o0.y = h0.y + pre[1]*0.0625f + b2v[1];
    o0.z = h0.z + pre[2]*0.0625f + b2v[2];
    o0.w = h0.w + pre[3]*0.0625f + b2v[3];
    o1.x = h1.x + pre[4]*0.0625f + b2v[4];
    o1.y = h1.y + pre[5]*0.0625f + b2v[5];
    o1.z = h1.z + pre[6]*0.0625f + b2v[6];
    o1.w = h1.w + pre[7]*0.0625f + b2v[7];
    ((float4*)op)[0] = o0;
    ((float4*)op)[1] = o1;
  }
}

extern "C" void kernel_launch(void* const* d_in, const int* in_sizes, int n_in,
                              void* d_out, int out_size, void* d_ws, size_t ws_size,
                              hipStream_t stream){
  const float* hidden = (const float*)d_in[0];
  // d_in[1] attention_mask: all-true, no-op in reference -> ignored
  const float* cosT = (const float*)d_in[2];
  const float* sinT = (const float*)d_in[3];
  const float* wq_a = (const float*)d_in[4];
  const float* wq_b = (const float*)d_in[5];
  const float* bq   = (const float*)d_in[6];
  const float* wk_a = (const float*)d_in[7];
  const float* wk_b = (const float*)d_in[8];
  const float* bk   = (const float*)d_in[9];
  const float* wv_a = (const float*)d_in[10];
  const float* wv_b = (const float*)d_in[11];
  const float* bv   = (const float*)d_in[12];
  const float* nqw  = (const float*)d_in[13];
  const float* nqb  = (const float*)d_in[14];
  const float* nkw  = (const float*)d_in[15];
  const float* nkb  = (const float*)d_in[16];
  const float* w1a  = (const float*)d_in[17];
  const float* w1b  = (const float*)d_in[18];
  const float* b1   = (const float*)d_in[19];
  const float* w3a  = (const float*)d_in[20];
  const float* w3b  = (const float*)d_in[21];
  const float* b3   = (const float*)d_in[22];
  const float* w2a  = (const float*)d_in[23];
  const float* w2b  = (const float*)d_in[24];
  const float* b2   = (const float*)d_in[25];
  const float* normw  = (const float*)d_in[26];
  const float* fnormw = (const float*)d_in[27];
  float* out = (float*)d_out;

  // ws layout (~53 MB)
  char* p = (char*)d_ws;
  u16* bufA = (u16*)p; p += (size_t)NROWS*DIM*2;       // nh, then nf
  u16* qbuf = (u16*)p; p += (size_t)NROWS*DIM*2;       // q bf16 (exp2-scaled)
  u16* kbuf = (u16*)p; p += (size_t)NROWS*1024*2;
  u16* vbuf = (u16*)p; p += (size_t)NROWS*1024*2;
  float* xa   = (float*)p; p += (size_t)NROWS*48*4;
  float* t13  = (float*)p; p += (size_t)NROWS*32*4;
  float* racc = (float*)p; p += (size_t)NROWS*16*4;
  u16* wpk  = (u16*)p; p += (size_t)INNER*48*2;        // packed FFN weights bf16

  k_pack<<<INNER/256,256,0,stream>>>(w1b, w3b, w2a, wpk);
  k_rms<<<NROWS,256,0,stream>>>(hidden, normw, bufA);                       // nh
  k_loraAm<3><<<192,256,0,stream>>>(bufA, wq_a, wk_a, wv_a, xa);
  k_qb <<<NROWS/16,256,0,stream>>>(xa, wq_b, bq, nqw, nqb, cosT, sinT, qbuf);
  k_kvb<<<NROWS/16,256,0,stream>>>(xa, wk_b, bk, nkw, nkb, wv_b, bv, cosT, sinT, kbuf, vbuf);
  k_attn<<<512,512,0,stream>>>(qbuf, kbuf, vbuf, hidden, out);              // out = h
  k_rms<<<NROWS,256,0,stream>>>(out, fnormw, bufA);                         // nf
  k_loraAm<2><<<128,256,0,stream>>>(bufA, w1a, w3a, nullptr, t13);
  k_ffn<<<NROWS/4,256,0,stream>>>(t13, wpk, b1, b3, racc);
  k_out<<<NROWS/16,256,0,stream>>>(racc, w2b, b2, out);
}